// Round 8
// baseline (191.083 us; speedup 1.0000x reference)
//
#include <hip/hip_runtime.h>
#include <hip/hip_bf16.h>

typedef __bf16 bf16;
typedef __bf16 bf16x4 __attribute__((ext_vector_type(4)));
typedef __bf16 bf16x8 __attribute__((ext_vector_type(8)));
typedef float f32x4 __attribute__((ext_vector_type(4)));

typedef __attribute__((address_space(3))) void lds_void;
typedef const __attribute__((address_space(1))) void gbl_void;

#define D_MODEL 1024
#define NHEAD 16
#define DEPTH 64
#define SEQ 2048
#define BATCH 2
#define NTOK (BATCH * SEQ)   // 4096

// 1/sqrt(64) * log2(e): folded into q so attention exp is a bare exp2.
#define Q_SCALE 0.18033688f

// ---------------------------------------------------------------------------
// Kernel 1: prep = weight transpose+convert (z=0..3) + x convert (z=4..7).
// ---------------------------------------------------------------------------
__global__ __launch_bounds__(256) void prep(const float* __restrict__ w0,
                                            const float* __restrict__ w1,
                                            const float* __restrict__ w2,
                                            const float* __restrict__ w3,
                                            const float* __restrict__ x,
                                            bf16* __restrict__ wtb,
                                            bf16* __restrict__ xb) {
    int z = blockIdx.z;
    int tx = threadIdx.x, ty = threadIdx.y;   // (32, 8)
    if (z < 4) {
        const float* w = (z == 0) ? w0 : (z == 1) ? w1 : (z == 2) ? w2 : w3;
        bf16* d = wtb + (size_t)z * D_MODEL * D_MODEL;
        __shared__ float tile[32][33];
        int c0 = blockIdx.x * 32;   // source col block (n)
        int r0 = blockIdx.y * 32;   // source row block (k)
#pragma unroll
        for (int i = 0; i < 4; i++)
            tile[ty + i * 8][tx] = w[(size_t)(r0 + ty + i * 8) * D_MODEL + c0 + tx];
        __syncthreads();
#pragma unroll
        for (int i = 0; i < 4; i++)
            d[(size_t)(c0 + ty + i * 8) * D_MODEL + r0 + tx] = (bf16)tile[tx][ty + i * 8];
    } else {
        int t = ty * 32 + tx;
        size_t i = ((size_t)(z - 4) * 1024 + blockIdx.y * 32 + blockIdx.x) * 256 + t;
        float4 v = ((const float4*)x)[i];
        bf16x4 o = {(bf16)v.x, (bf16)v.y, (bf16)v.z, (bf16)v.w};
        *(bf16x4*)&xb[i * 4] = o;
    }
}

// ---------------------------------------------------------------------------
// Kernel 2: QKV projection, 256x256 tile, BK=64, 8 waves, 8-phase counted
// vmcnt schedule (unchanged this round).
// ---------------------------------------------------------------------------
__global__ __launch_bounds__(512, 2) void qkv_gemm(const bf16* __restrict__ xb,
                                                   const bf16* __restrict__ wtb,
                                                   const float* __restrict__ bq,
                                                   const float* __restrict__ bk,
                                                   const float* __restrict__ bv,
                                                   bf16* __restrict__ q,
                                                   bf16* __restrict__ k,
                                                   bf16* __restrict__ v) {
    __shared__ bf16 sm[65536];   // 128 KiB

    const int flat = blockIdx.x;
    const int wg = (flat & 7) * 24 + (flat >> 3);
    const int mt = wg & 15, nt = wg >> 4;     // wg = nt*16 + mt
    const int row0 = mt << 8;                 // token base
    const int z = nt >> 2;                    // 0=q 1=k 2=v
    const int nb = (nt & 3) << 8;             // feature base within z

    const int tid = threadIdx.x;
    const int lane = tid & 63, wave = tid >> 6;
    const int wm = wave >> 2, wn = wave & 3;  // 2 x 4 wave grid
    const int quad = lane >> 4, l16 = lane & 15;
    const int kch = ((quad ^ ((l16 >> 1) & 3)) << 3);   // swizzled 16B chunk (elems)

    const int srow = lane >> 2;
    const int scg = (lane & 3) ^ ((lane >> 3) & 3);     // pre-swizzled src chunk
    const int stDst = wave * 1024 + lane * 8;           // elems within half

    const bf16* Ag = xb + (size_t)(row0 + wave * 32 + srow) * D_MODEL + scg * 8;
    const bf16* Bg = wtb + (size_t)z * D_MODEL * D_MODEL
                   + (size_t)(nb + wave * 32 + srow) * D_MODEL + scg * 8;

    f32x4 acc[8][4] = {};
    bf16x8 bfr[4];

#define GLL(SRC, DST) __builtin_amdgcn_global_load_lds((gbl_void*)(SRC), (lds_void*)(DST), 16, 0, 0)
#define STG_A(T_, KQ_, BUF_) { \
    const bf16* s_ = Ag + (T_) * 64 + (KQ_) * 32; \
    bf16* d_ = sm + (BUF_) * 16384 + (KQ_) * 8192 + stDst; \
    GLL(s_, d_); GLL(s_ + 16 * D_MODEL, d_ + 512); }
#define STG_B(T_, KQ_, BUF_) { \
    const bf16* s_ = Bg + (T_) * 64 + (KQ_) * 32; \
    bf16* d_ = sm + 32768 + (BUF_) * 16384 + (KQ_) * 8192 + stDst; \
    GLL(s_, d_); GLL(s_ + 16 * D_MODEL, d_ + 512); }
#define WAIT6 { asm volatile("s_waitcnt vmcnt(6)" ::: "memory"); }
#define NOW

#define PHASE(BUF_, KQ_, MQ_, STG_STMT, WAIT_STMT) { \
    bf16x8 af[4]; \
    const int ab_ = (BUF_) * 16384 + (KQ_) * 8192 + (wm * 128 + (MQ_) * 64 + l16) * 32 + kch; \
    _Pragma("unroll") \
    for (int i_ = 0; i_ < 4; i_++) af[i_] = *(const bf16x8*)&sm[ab_ + i_ * 512]; \
    if ((MQ_) == 0) { \
        const int bb_ = 32768 + (BUF_) * 16384 + (KQ_) * 8192 + (wn * 64 + l16) * 32 + kch; \
        _Pragma("unroll") \
        for (int j_ = 0; j_ < 4; j_++) bfr[j_] = *(const bf16x8*)&sm[bb_ + j_ * 512]; \
    } \
    STG_STMT; \
    WAIT_STMT; \
    __builtin_amdgcn_sched_barrier(0); \
    __builtin_amdgcn_s_barrier(); \
    __builtin_amdgcn_s_setprio(1); \
    _Pragma("unroll") \
    for (int i_ = 0; i_ < 4; i_++) \
        _Pragma("unroll") \
        for (int j_ = 0; j_ < 4; j_++) \
            acc[(MQ_) * 4 + i_][j_] = __builtin_amdgcn_mfma_f32_16x16x32_bf16( \
                af[i_], bfr[j_], acc[(MQ_) * 4 + i_][j_], 0, 0, 0); \
    __builtin_amdgcn_s_setprio(0); \
    __builtin_amdgcn_sched_barrier(0); \
    __builtin_amdgcn_s_barrier(); }

    STG_B(0, 0, 0);
    STG_A(0, 0, 0);
    STG_B(0, 1, 0);
    STG_A(0, 1, 0);
    asm volatile("s_waitcnt vmcnt(4)" ::: "memory");
    STG_B(1, 0, 1);
    STG_A(1, 0, 1);
    STG_B(1, 1, 1);
    asm volatile("s_waitcnt vmcnt(6)" ::: "memory");
    __builtin_amdgcn_sched_barrier(0);
    __builtin_amdgcn_s_barrier();

#pragma unroll 1
    for (int it = 0; it < 8; ++it) {
        const int t1 = 2 * it + 1;
        const int t2 = (2 * it + 2) & 15;   // wrap keeps vmcnt counts exact at tail
        const int t3 = (2 * it + 3) & 15;
        PHASE(0, 0, 0, STG_A(t1, 1, 1), NOW)      // ph1
        PHASE(0, 0, 1, STG_B(t2, 0, 0), NOW)      // ph2
        PHASE(0, 1, 0, STG_A(t2, 0, 0), NOW)      // ph3
        PHASE(0, 1, 1, STG_B(t2, 1, 0), WAIT6)    // ph4
        PHASE(1, 0, 0, STG_A(t2, 1, 0), NOW)      // ph5
        PHASE(1, 0, 1, STG_B(t3, 0, 1), NOW)      // ph6
        PHASE(1, 1, 0, STG_A(t3, 0, 1), NOW)      // ph7
        PHASE(1, 1, 1, STG_B(t3, 1, 1), WAIT6)    // ph8
    }

#undef PHASE
#undef WAIT6
#undef NOW
#undef STG_A
#undef STG_B
#undef GLL

    const float* bias = (z == 0) ? bq : (z == 1) ? bk : bv;
    const int bI = row0 >> 11;
    const int sBase = row0 & 2047;
    if (z < 2) {
        bf16* dst = (z == 0) ? q : k;   // [B,H,S,64]
        const float scl = (z == 0) ? Q_SCALE : 1.0f;
#pragma unroll
        for (int j = 0; j < 4; j++) {
            const int f = nb + wn * 64 + j * 16 + l16;
            const float bi = bias[f];
            const int hh = f >> 6, d = f & 63;
            bf16* dcol = dst + ((size_t)(bI * NHEAD + hh) * SEQ) * DEPTH + d;
#pragma unroll
            for (int mi = 0; mi < 8; mi++) {
                const int s0 = sBase + wm * 128 + (mi >> 2) * 64 + (mi & 3) * 16 + quad * 4;
#pragma unroll
                for (int r = 0; r < 4; r++)
                    dcol[(size_t)(s0 + r) * DEPTH] = (bf16)((acc[mi][j][r] + bi) * scl);
            }
        }
    } else {
#pragma unroll
        for (int j = 0; j < 4; j++) {
            const int f = nb + wn * 64 + j * 16 + l16;
            const float bi = bias[f];
            const int hh = f >> 6, d = f & 63;
            bf16* vrow = v + ((size_t)(bI * NHEAD + hh) * DEPTH + d) * SEQ;
#pragma unroll
            for (int mi = 0; mi < 8; mi++) {
                const int s0 = sBase + wm * 128 + (mi >> 2) * 64 + (mi & 3) * 16 + quad * 4;
                f32x4 a = acc[mi][j];
                bf16x4 ob = {(bf16)(a[0] + bi), (bf16)(a[1] + bi),
                             (bf16)(a[2] + bi), (bf16)(a[3] + bi)};
                *(bf16x4*)&vrow[s0] = ob;
            }
        }
    }
}

// ---------------------------------------------------------------------------
// Kernel 3: flash attention, R11 == R7 (kv-split, per-wave private dbuf LDS,
// zero barriers in main loop, wave stagger w*4).  Measured 55.1 us in R7.
// ---------------------------------------------------------------------------
__global__ __launch_bounds__(256) void attn(const bf16* __restrict__ q,
                                            const bf16* __restrict__ k,
                                            const bf16* __restrict__ v,
                                            bf16* __restrict__ ctx) {
    __shared__ __align__(16) bf16 smb[32768];   // 64 KB: 4 waves x 16 KB
    const int tid = threadIdx.x;
    const int lane = tid & 63, wave = tid >> 6;
    const int quad = lane >> 4, l16 = lane & 15;
    const int bh = blockIdx.x;
    const int q0 = blockIdx.y * 64;
    const size_t hb = (size_t)bh * SEQ * DEPTH;
    const bf16* qh = q + hb;
    const bf16* kh = k + hb;            // [S][64]
    const bf16* vh = v + hb;            // [64][S]

    // Q as B-fragments: block's 64 q rows, shared by all waves
    bf16x8 bq_[4][2];
#pragma unroll
    for (int n = 0; n < 4; n++) {
        int qrow = q0 + n * 16 + l16;
#pragma unroll
        for (int c = 0; c < 2; c++)
            bq_[n][c] = *(const bf16x8*)&qh[(size_t)qrow * DEPTH + c * 32 + quad * 8];
    }

    f32x4 ov[4][4] = {};   // [d-tile][q-tile] kv-partial ctx^T
    f32x4 lv = {};         // [q-tile] quad-partial row sums

    // per-wave LDS bases (elems): K buf at wb + buf*2048, V at wb+4096+buf*2048
    const int wb = wave * 8192;
    // staging source swizzles
    const int kchS = (lane & 7) ^ (((lane >> 3) & 3) << 1);   // ^ (o&1) per o
    const int vchS = (lane & 3) ^ ((lane >> 2) & 3);
    // fragment-read geometry (R4 verified)
    const int krdL = ((l16 >> 2) << 3) + (l16 & 3);           // local row, + h*4
    const int ksw = ((l16 & 3) << 1) | ((l16 >> 2) & 1);      // = s(row)
    const int vsw = (quad ^ (l16 & 3)) << 3;                  // V read chunk

#define GLL(SRC, DST) __builtin_amdgcn_global_load_lds((gbl_void*)(SRC), (lds_void*)(DST), 16, 0, 0)

#define STAGE(BUF_, T_) { \
    _Pragma("unroll") \
    for (int o_ = 0; o_ < 4; o_++) { \
        const bf16* s_ = kh + (size_t)((T_) + wave * 32 + o_ * 8 + (lane >> 3)) * DEPTH \
                       + ((kchS ^ (o_ & 1)) << 3); \
        GLL(s_, smb + wb + (BUF_) * 2048 + o_ * 512 + lane * 8); \
    } \
    _Pragma("unroll") \
    for (int o_ = 0; o_ < 4; o_++) { \
        const bf16* s_ = vh + (size_t)(o_ * 16 + (lane >> 2)) * SEQ + (T_) + wave * 32 \
                       + (vchS << 3); \
        GLL(s_, smb + wb + 4096 + (BUF_) * 2048 + o_ * 512 + lane * 8); \
    } }

#define COMPUTE(BUF_) { \
    f32x4 s[2][4] = {}; \
    __builtin_amdgcn_s_setprio(1); \
    _Pragma("unroll") \
    for (int c_ = 0; c_ < 2; c_++) \
        _Pragma("unroll") \
        for (int h_ = 0; h_ < 2; h_++) { \
            bf16x8 kf = *(const bf16x8*)&smb[wb + (BUF_) * 2048 + (krdL + h_ * 4) * 64 \
                                             + ((((c_ << 2) | quad) ^ ksw) << 3)]; \
            _Pragma("unroll") \
            for (int n_ = 0; n_ < 4; n_++) \
                s[h_][n_] = __builtin_amdgcn_mfma_f32_16x16x32_bf16(kf, bq_[n_][c_], s[h_][n_], 0, 0, 0); \
        } \
    __builtin_amdgcn_s_setprio(0); \
    bf16x8 pb[4]; \
    _Pragma("unroll") \
    for (int n_ = 0; n_ < 4; n_++) { \
        float e0 = __builtin_amdgcn_exp2f(s[0][n_][0]); \
        float e1 = __builtin_amdgcn_exp2f(s[0][n_][1]); \
        float e2 = __builtin_amdgcn_exp2f(s[0][n_][2]); \
        float e3 = __builtin_amdgcn_exp2f(s[0][n_][3]); \
        float e4 = __builtin_amdgcn_exp2f(s[1][n_][0]); \
        float e5 = __builtin_amdgcn_exp2f(s[1][n_][1]); \
        float e6 = __builtin_amdgcn_exp2f(s[1][n_][2]); \
        float e7 = __builtin_amdgcn_exp2f(s[1][n_][3]); \
        pb[n_][0] = (bf16)e0; pb[n_][1] = (bf16)e1; \
        pb[n_][2] = (bf16)e2; pb[n_][3] = (bf16)e3; \
        pb[n_][4] = (bf16)e4; pb[n_][5] = (bf16)e5; \
        pb[n_][6] = (bf16)e6; pb[n_][7] = (bf16)e7; \
        lv[n_] += ((e0 + e1) + (e2 + e3)) + ((e4 + e5) + (e6 + e7)); \
    } \
    __builtin_amdgcn_s_setprio(1); \
    _Pragma("unroll") \
    for (int t_ = 0; t_ < 4; t_++) { \
        bf16x8 vf = *(const bf16x8*)&smb[wb + 4096 + (BUF_) * 2048 + (t_ * 16 + l16) * 32 + vsw]; \
        _Pragma("unroll") \
        for (int n_ = 0; n_ < 4; n_++) \
            ov[t_][n_] = __builtin_amdgcn_mfma_f32_16x16x32_bf16(vf, pb[n_], ov[t_][n_], 0, 0, 0); \
    } \
    __builtin_amdgcn_s_setprio(0); }

#define WAITV(N_) { asm volatile("s_waitcnt vmcnt(" #N_ ")" ::: "memory"); }
#define SB0 __builtin_amdgcn_sched_barrier(0)

    // wave-staggered tile order: ts(i) = ((i + wave*4) & 15) * 128
    const int tb = wave << 2;
    STAGE(0, ((tb) & 15) * 128);
#pragma unroll 1
    for (int i = 0; i < 16; i++) {
        if (i < 15) {
            STAGE((i + 1) & 1, ((tb + i + 1) & 15) * 128);
            WAITV(8);
        } else {
            WAITV(0);
        }
        SB0;
        COMPUTE(i & 1);
        SB0;
    }

#undef SB0
#undef WAITV
#undef COMPUTE
#undef STAGE
#undef GLL

    // ---- cross-wave reduction of kv-partials (R4 verified; reuses LDS) ----
    f32x4* Red  = (f32x4*)smb;                       // [8 tiles][4 waves][64] 32 KB
    f32x4* Lred = (f32x4*)((char*)smb + 32768);      // [4 waves][64]           4 KB
    __syncthreads();
#pragma unroll
    for (int tt = 0; tt < 8; tt++)
        Red[(tt * 4 + wave) * 64 + lane] = ov[tt >> 2][tt & 3];
    Lred[wave * 64 + lane] = lv;
    __syncthreads();
    f32x4 ls = {};
#pragma unroll
    for (int w_ = 0; w_ < 4; w_++)
#pragma unroll
        for (int qd = 0; qd < 4; qd++)
            ls += Lred[w_ * 64 + qd * 16 + l16];
    const int b = bh >> 4, hh = bh & 15;
    const int wb1 = wave & 1;
#pragma unroll
    for (int u = 0; u < 2; u++) {
        int tt = wave * 2 + u;
        f32x4 sv = Red[(tt * 4 + 0) * 64 + lane] + Red[(tt * 4 + 1) * 64 + lane]
                 + Red[(tt * 4 + 2) * 64 + lane] + Red[(tt * 4 + 3) * 64 + lane];
        int n = wb1 * 2 + u, t = wave >> 1;
        float iv = 1.0f / (wb1 ? ls[2 + u] : ls[u]);
        bf16x4 ob = {(bf16)(sv[0] * iv), (bf16)(sv[1] * iv),
                     (bf16)(sv[2] * iv), (bf16)(sv[3] * iv)};
        size_t off = ((size_t)(b * SEQ + q0 + n * 16 + l16)) * D_MODEL
                   + hh * 64 + t * 16 + quad * 4;
        *(bf16x4*)&ctx[off] = ob;
    }
    __syncthreads();
#pragma unroll
    for (int tt = 8; tt < 16; tt++)
        Red[((tt - 8) * 4 + wave) * 64 + lane] = ov[tt >> 2][tt & 3];
    __syncthreads();
#pragma unroll
    for (int u = 0; u < 2; u++) {
        int rt = wave * 2 + u;
        f32x4 sv = Red[(rt * 4 + 0) * 64 + lane] + Red[(rt * 4 + 1) * 64 + lane]
                 + Red[(rt * 4 + 2) * 64 + lane] + Red[(rt * 4 + 3) * 64 + lane];
        int n = wb1 * 2 + u, t = 2 + (wave >> 1);
        float iv = 1.0f / (wb1 ? ls[2 + u] : ls[u]);
        bf16x4 ob = {(bf16)(sv[0] * iv), (bf16)(sv[1] * iv),
                     (bf16)(sv[2] * iv), (bf16)(sv[3] * iv)};
        size_t off = ((size_t)(b * SEQ + q0 + n * 16 + l16)) * D_MODEL
                   + hh * 64 + t * 16 + quad * 4;
        *(bf16x4*)&ctx[off] = ob;
    }
}

// ---------------------------------------------------------------------------
// Kernel 4: output projection — REVERTED to the R6-measured version
// (64x128 tiles, grid (8,64) = 512 blocks = 2 blocks/CU, 12 KB LDS).
// The R7 rewrite (128^2, 256 blocks = 1 block/CU) regressed ~+10 us:
// cross-XCD ctx reads with no co-resident block to hide latency.
// ---------------------------------------------------------------------------
__global__ __launch_bounds__(256) void out_gemm(const bf16* __restrict__ ctx,
                                                const bf16* __restrict__ wot,
                                                const float* __restrict__ bo,
                                                float* __restrict__ out) {
    __shared__ bf16 As[64 * 32];
    __shared__ bf16 Bs[128 * 32];
    const int tid = threadIdx.x;
    const int lane = tid & 63, wave = tid >> 6;
    const int quad = lane >> 4, l16 = lane & 15;
    const int srow = lane >> 2, selem = (lane & 3) * 8;
    int row0 = blockIdx.y * 64, col0 = blockIdx.x * 128;
    f32x4 acc[4][2] = {};

    for (int k0 = 0; k0 < D_MODEL; k0 += 32) {
        __syncthreads();
        {
            const bf16* ga = ctx + (size_t)(row0 + wave * 16 + srow) * D_MODEL + k0 + selem;
            __builtin_amdgcn_global_load_lds((gbl_void*)ga, (lds_void*)(As + wave * 512 + lane * 8), 16, 0, 0);
        }
#pragma unroll
        for (int t = 0; t < 2; t++) {
            int m = wave * 2 + t;
            const bf16* gb = wot + (size_t)(col0 + m * 16 + srow) * D_MODEL + k0 + selem;
            __builtin_amdgcn_global_load_lds((gbl_void*)gb, (lds_void*)(Bs + m * 512 + lane * 8), 16, 0, 0);
        }
        __syncthreads();
        bf16x8 af[4], bfr[2];
#pragma unroll
        for (int i = 0; i < 4; i++)
            af[i] = *(const bf16x8*)&As[(i * 16 + l16) * 32 + quad * 8];
#pragma unroll
        for (int j = 0; j < 2; j++)
            bfr[j] = *(const bf16x8*)&Bs[(wave * 32 + j * 16 + l16) * 32 + quad * 8];
#pragma unroll
        for (int i = 0; i < 4; i++)
#pragma unroll
            for (int j = 0; j < 2; j++)
                acc[i][j] = __builtin_amdgcn_mfma_f32_16x16x32_bf16(af[i], bfr[j], acc[i][j], 0, 0, 0);
    }
#pragma unroll
    for (int i = 0; i < 4; i++)
#pragma unroll
        for (int j = 0; j < 2; j++) {
            int colg = col0 + wave * 32 + j * 16 + l16;
            float bi = bo[colg];
            int rbase = row0 + i * 16 + quad * 4;
#pragma unroll
            for (int r = 0; r < 4; r++)
                out[(size_t)(rbase + r) * D_MODEL + colg] = acc[i][j][r] + bi;
        }
}

// ---------------------------------------------------------------------------
extern "C" void kernel_launch(void* const* d_in, const int* in_sizes, int n_in,
                              void* d_out, int out_size, void* d_ws, size_t ws_size,
                              hipStream_t stream) {
    const float* x  = (const float*)d_in[0];
    const float* wq = (const float*)d_in[1];
    const float* bq = (const float*)d_in[2];
    const float* wk = (const float*)d_in[3];
    const float* bk = (const float*)d_in[4];
    const float* wv = (const float*)d_in[5];
    const float* bv = (const float*)d_in[6];
    const float* wo = (const float*)d_in[7];
    const float* bo = (const float*)d_in[8];
    float* out = (float*)d_out;

    const size_t MB = 1024 * 1024;
    char* ws = (char*)d_ws;
    bf16* xb  = (bf16*)(ws);             // [4096][1024]            8 MB
    bf16* wtb = (bf16*)(ws + 8 * MB);    // [4][1024][1024] (N,K)   8 MB
    bf16* qb  = (bf16*)(ws + 16 * MB);   // [B,H,S,64] (scaled)     8 MB
    bf16* kb  = (bf16*)(ws + 24 * MB);   // [B,H,S,64]              8 MB
    bf16* vb  = (bf16*)(ws + 32 * MB);   // [B,H,64,S]              8 MB
    bf16* ctx = (bf16*)(ws + 40 * MB);   // [4096][1024]            8 MB

    prep<<<dim3(32, 32, 8), dim3(32, 8), 0, stream>>>(wq, wk, wv, wo, x, wtb, xb);
    qkv_gemm<<<dim3(192), dim3(512), 0, stream>>>(xb, wtb, bq, bk, bv, qb, kb, vb);
    attn<<<dim3(BATCH * NHEAD, SEQ / 64), 256, 0, stream>>>(qb, kb, vb, ctx);
    out_gemm<<<dim3(8, 64), 256, 0, stream>>>(ctx, wtb + 3 * (size_t)D_MODEL * D_MODEL, bo, out);
}

// Round 9
// 190.969 us; speedup vs baseline: 1.0006x; 1.0006x over previous
//
#include <hip/hip_runtime.h>
#include <hip/hip_bf16.h>

typedef __bf16 bf16;
typedef __bf16 bf16x4 __attribute__((ext_vector_type(4)));
typedef __bf16 bf16x8 __attribute__((ext_vector_type(8)));
typedef float f32x4 __attribute__((ext_vector_type(4)));

typedef __attribute__((address_space(3))) void lds_void;
typedef const __attribute__((address_space(1))) void gbl_void;

#define D_MODEL 1024
#define NHEAD 16
#define DEPTH 64
#define SEQ 2048
#define BATCH 2
#define NTOK (BATCH * SEQ)   // 4096

// 1/sqrt(64) * log2(e): folded into q so attention exp is a bare exp2.
#define Q_SCALE 0.18033688f

// ---------------------------------------------------------------------------
// Kernel 1: prep = weight transpose+convert (z=0..3) + x convert (z=4..7).
// ---------------------------------------------------------------------------
__global__ __launch_bounds__(256) void prep(const float* __restrict__ w0,
                                            const float* __restrict__ w1,
                                            const float* __restrict__ w2,
                                            const float* __restrict__ w3,
                                            const float* __restrict__ x,
                                            bf16* __restrict__ wtb,
                                            bf16* __restrict__ xb) {
    int z = blockIdx.z;
    int tx = threadIdx.x, ty = threadIdx.y;   // (32, 8)
    if (z < 4) {
        const float* w = (z == 0) ? w0 : (z == 1) ? w1 : (z == 2) ? w2 : w3;
        bf16* d = wtb + (size_t)z * D_MODEL * D_MODEL;
        __shared__ float tile[32][33];
        int c0 = blockIdx.x * 32;   // source col block (n)
        int r0 = blockIdx.y * 32;   // source row block (k)
#pragma unroll
        for (int i = 0; i < 4; i++)
            tile[ty + i * 8][tx] = w[(size_t)(r0 + ty + i * 8) * D_MODEL + c0 + tx];
        __syncthreads();
#pragma unroll
        for (int i = 0; i < 4; i++)
            d[(size_t)(c0 + ty + i * 8) * D_MODEL + r0 + tx] = (bf16)tile[tx][ty + i * 8];
    } else {
        int t = ty * 32 + tx;
        size_t i = ((size_t)(z - 4) * 1024 + blockIdx.y * 32 + blockIdx.x) * 256 + t;
        float4 v = ((const float4*)x)[i];
        bf16x4 o = {(bf16)v.x, (bf16)v.y, (bf16)v.z, (bf16)v.w};
        *(bf16x4*)&xb[i * 4] = o;
    }
}

// ---------------------------------------------------------------------------
// Kernel 2: QKV projection, 256x256 tile, BK=64, 8 waves, 8-phase counted
// vmcnt schedule (unchanged this round).
// ---------------------------------------------------------------------------
__global__ __launch_bounds__(512, 2) void qkv_gemm(const bf16* __restrict__ xb,
                                                   const bf16* __restrict__ wtb,
                                                   const float* __restrict__ bq,
                                                   const float* __restrict__ bk,
                                                   const float* __restrict__ bv,
                                                   bf16* __restrict__ q,
                                                   bf16* __restrict__ k,
                                                   bf16* __restrict__ v) {
    __shared__ bf16 sm[65536];   // 128 KiB

    const int flat = blockIdx.x;
    const int wg = (flat & 7) * 24 + (flat >> 3);
    const int mt = wg & 15, nt = wg >> 4;     // wg = nt*16 + mt
    const int row0 = mt << 8;                 // token base
    const int z = nt >> 2;                    // 0=q 1=k 2=v
    const int nb = (nt & 3) << 8;             // feature base within z

    const int tid = threadIdx.x;
    const int lane = tid & 63, wave = tid >> 6;
    const int wm = wave >> 2, wn = wave & 3;  // 2 x 4 wave grid
    const int quad = lane >> 4, l16 = lane & 15;
    const int kch = ((quad ^ ((l16 >> 1) & 3)) << 3);   // swizzled 16B chunk (elems)

    const int srow = lane >> 2;
    const int scg = (lane & 3) ^ ((lane >> 3) & 3);     // pre-swizzled src chunk
    const int stDst = wave * 1024 + lane * 8;           // elems within half

    const bf16* Ag = xb + (size_t)(row0 + wave * 32 + srow) * D_MODEL + scg * 8;
    const bf16* Bg = wtb + (size_t)z * D_MODEL * D_MODEL
                   + (size_t)(nb + wave * 32 + srow) * D_MODEL + scg * 8;

    f32x4 acc[8][4] = {};
    bf16x8 bfr[4];

#define GLL(SRC, DST) __builtin_amdgcn_global_load_lds((gbl_void*)(SRC), (lds_void*)(DST), 16, 0, 0)
#define STG_A(T_, KQ_, BUF_) { \
    const bf16* s_ = Ag + (T_) * 64 + (KQ_) * 32; \
    bf16* d_ = sm + (BUF_) * 16384 + (KQ_) * 8192 + stDst; \
    GLL(s_, d_); GLL(s_ + 16 * D_MODEL, d_ + 512); }
#define STG_B(T_, KQ_, BUF_) { \
    const bf16* s_ = Bg + (T_) * 64 + (KQ_) * 32; \
    bf16* d_ = sm + 32768 + (BUF_) * 16384 + (KQ_) * 8192 + stDst; \
    GLL(s_, d_); GLL(s_ + 16 * D_MODEL, d_ + 512); }
#define WAIT6 { asm volatile("s_waitcnt vmcnt(6)" ::: "memory"); }
#define NOW

#define PHASE(BUF_, KQ_, MQ_, STG_STMT, WAIT_STMT) { \
    bf16x8 af[4]; \
    const int ab_ = (BUF_) * 16384 + (KQ_) * 8192 + (wm * 128 + (MQ_) * 64 + l16) * 32 + kch; \
    _Pragma("unroll") \
    for (int i_ = 0; i_ < 4; i_++) af[i_] = *(const bf16x8*)&sm[ab_ + i_ * 512]; \
    if ((MQ_) == 0) { \
        const int bb_ = 32768 + (BUF_) * 16384 + (KQ_) * 8192 + (wn * 64 + l16) * 32 + kch; \
        _Pragma("unroll") \
        for (int j_ = 0; j_ < 4; j_++) bfr[j_] = *(const bf16x8*)&sm[bb_ + j_ * 512]; \
    } \
    STG_STMT; \
    WAIT_STMT; \
    __builtin_amdgcn_sched_barrier(0); \
    __builtin_amdgcn_s_barrier(); \
    __builtin_amdgcn_s_setprio(1); \
    _Pragma("unroll") \
    for (int i_ = 0; i_ < 4; i_++) \
        _Pragma("unroll") \
        for (int j_ = 0; j_ < 4; j_++) \
            acc[(MQ_) * 4 + i_][j_] = __builtin_amdgcn_mfma_f32_16x16x32_bf16( \
                af[i_], bfr[j_], acc[(MQ_) * 4 + i_][j_], 0, 0, 0); \
    __builtin_amdgcn_s_setprio(0); \
    __builtin_amdgcn_sched_barrier(0); \
    __builtin_amdgcn_s_barrier(); }

    STG_B(0, 0, 0);
    STG_A(0, 0, 0);
    STG_B(0, 1, 0);
    STG_A(0, 1, 0);
    asm volatile("s_waitcnt vmcnt(4)" ::: "memory");
    STG_B(1, 0, 1);
    STG_A(1, 0, 1);
    STG_B(1, 1, 1);
    asm volatile("s_waitcnt vmcnt(6)" ::: "memory");
    __builtin_amdgcn_sched_barrier(0);
    __builtin_amdgcn_s_barrier();

#pragma unroll 1
    for (int it = 0; it < 8; ++it) {
        const int t1 = 2 * it + 1;
        const int t2 = (2 * it + 2) & 15;   // wrap keeps vmcnt counts exact at tail
        const int t3 = (2 * it + 3) & 15;
        PHASE(0, 0, 0, STG_A(t1, 1, 1), NOW)      // ph1
        PHASE(0, 0, 1, STG_B(t2, 0, 0), NOW)      // ph2
        PHASE(0, 1, 0, STG_A(t2, 0, 0), NOW)      // ph3
        PHASE(0, 1, 1, STG_B(t2, 1, 0), WAIT6)    // ph4
        PHASE(1, 0, 0, STG_A(t2, 1, 0), NOW)      // ph5
        PHASE(1, 0, 1, STG_B(t3, 0, 1), NOW)      // ph6
        PHASE(1, 1, 0, STG_A(t3, 0, 1), NOW)      // ph7
        PHASE(1, 1, 1, STG_B(t3, 1, 1), WAIT6)    // ph8
    }

#undef PHASE
#undef WAIT6
#undef NOW
#undef STG_A
#undef STG_B
#undef GLL

    const float* bias = (z == 0) ? bq : (z == 1) ? bk : bv;
    const int bI = row0 >> 11;
    const int sBase = row0 & 2047;
    if (z < 2) {
        bf16* dst = (z == 0) ? q : k;   // [B,H,S,64]
        const float scl = (z == 0) ? Q_SCALE : 1.0f;
#pragma unroll
        for (int j = 0; j < 4; j++) {
            const int f = nb + wn * 64 + j * 16 + l16;
            const float bi = bias[f];
            const int hh = f >> 6, d = f & 63;
            bf16* dcol = dst + ((size_t)(bI * NHEAD + hh) * SEQ) * DEPTH + d;
#pragma unroll
            for (int mi = 0; mi < 8; mi++) {
                const int s0 = sBase + wm * 128 + (mi >> 2) * 64 + (mi & 3) * 16 + quad * 4;
#pragma unroll
                for (int r = 0; r < 4; r++)
                    dcol[(size_t)(s0 + r) * DEPTH] = (bf16)((acc[mi][j][r] + bi) * scl);
            }
        }
    } else {
#pragma unroll
        for (int j = 0; j < 4; j++) {
            const int f = nb + wn * 64 + j * 16 + l16;
            const float bi = bias[f];
            const int hh = f >> 6, d = f & 63;
            bf16* vrow = v + ((size_t)(bI * NHEAD + hh) * DEPTH + d) * SEQ;
#pragma unroll
            for (int mi = 0; mi < 8; mi++) {
                const int s0 = sBase + wm * 128 + (mi >> 2) * 64 + (mi & 3) * 16 + quad * 4;
                f32x4 a = acc[mi][j];
                bf16x4 ob = {(bf16)(a[0] + bi), (bf16)(a[1] + bi),
                             (bf16)(a[2] + bi), (bf16)(a[3] + bi)};
                *(bf16x4*)&vrow[s0] = ob;
            }
        }
    }
}

// ---------------------------------------------------------------------------
// Kernel 3: flash attention, R12: 8-wave block = 2 q-groups x 4 kv-slices.
// Wave (qg,ks) computes 32 q rows (qg half) x 32-kv slice ks — the R4/R6
// verified kv-split token map with wave->ks and n-range 4->2.  The two waves
// sharing slice ks read the SAME LDS buffers; only qg=0 stages (halves GLL
// traffic).  Sync per tile = the qkv-proven pattern:
//   { qg0: STAGE(next buf) + vmcnt(8) } -> barrier -> COMPUTE(cur) -> barrier
// Counted vmcnt (never 0 in loop) keeps next-tile loads in flight across
// barriers; visibility proof identical to qkv's cross-wave staging.
// LDS 64 KB (4 slices x 2 buf x (4K K + 4K V)) -> 2 blocks/CU x 8 waves =
// 4 waves/SIMD (vs R8's 2): two independent blocks per SIMD de-phase-lock
// the pipes (replaces R7's intra-block stagger).  Reduction: partials over
// ks per (qg,t,n) in 2 rounds through the staging LDS; 8 waves <-> 8 output
// combos per round.  XCD pinning: block id = bh + 32*qb -> XCD bh%8.
// ---------------------------------------------------------------------------
__global__ __launch_bounds__(512, 4) void attn(const bf16* __restrict__ q,
                                               const bf16* __restrict__ k,
                                               const bf16* __restrict__ v,
                                               bf16* __restrict__ ctx) {
    __shared__ __align__(16) bf16 smb[32768];   // 64 KB: 4 slices x 16 KB
    const int tid = threadIdx.x;
    const int lane = tid & 63, wave = tid >> 6;   // 8 waves
    const int ks = wave & 3, qg = wave >> 2;
    const int quad = lane >> 4, l16 = lane & 15;
    const int bh = blockIdx.x;
    const int q0 = blockIdx.y * 64;
    const size_t hb = (size_t)bh * SEQ * DEPTH;
    const bf16* qh = q + hb;
    const bf16* kh = k + hb;            // [S][64]
    const bf16* vh = v + hb;            // [64][S]

    // Q as B-fragments: this wave's 32 q rows (qg half)
    bf16x8 bq_[2][2];
#pragma unroll
    for (int n = 0; n < 2; n++) {
        int qrow = q0 + qg * 32 + n * 16 + l16;
#pragma unroll
        for (int c = 0; c < 2; c++)
            bq_[n][c] = *(const bf16x8*)&qh[(size_t)qrow * DEPTH + c * 32 + quad * 8];
    }

    f32x4 ov[4][2] = {};        // [d-tile][q-tile] kv-partial ctx^T
    float lvs[2] = {0.f, 0.f};  // [q-tile] quad-partial row sums

    // slice LDS base (elems): K at sb + buf*2048, V at sb + 4096 + buf*2048
    const int sb = ks * 8192;
    // staging source swizzles (used by qg==0 only)
    const int kchS = (lane & 7) ^ (((lane >> 3) & 3) << 1);   // ^ (o&1) per o
    const int vchS = (lane & 3) ^ ((lane >> 2) & 3);
    // fragment-read geometry (R4/R6 verified)
    const int krdL = ((l16 >> 2) << 3) + (l16 & 3);           // local row, + h*4
    const int ksw = ((l16 & 3) << 1) | ((l16 >> 2) & 1);      // = s(row)
    const int vsw = (quad ^ (l16 & 3)) << 3;                  // V read chunk

#define GLL(SRC, DST) __builtin_amdgcn_global_load_lds((gbl_void*)(SRC), (lds_void*)(DST), 16, 0, 0)

#define STAGE(BUF_, T_) { \
    _Pragma("unroll") \
    for (int o_ = 0; o_ < 4; o_++) { \
        const bf16* s_ = kh + (size_t)((T_) + ks * 32 + o_ * 8 + (lane >> 3)) * DEPTH \
                       + ((kchS ^ (o_ & 1)) << 3); \
        GLL(s_, smb + sb + (BUF_) * 2048 + o_ * 512 + lane * 8); \
    } \
    _Pragma("unroll") \
    for (int o_ = 0; o_ < 4; o_++) { \
        const bf16* s_ = vh + (size_t)(o_ * 16 + (lane >> 2)) * SEQ + (T_) + ks * 32 \
                       + (vchS << 3); \
        GLL(s_, smb + sb + 4096 + (BUF_) * 2048 + o_ * 512 + lane * 8); \
    } }

#define COMPUTE(BUF_) { \
    f32x4 s[2][2] = {}; \
    __builtin_amdgcn_s_setprio(1); \
    _Pragma("unroll") \
    for (int c_ = 0; c_ < 2; c_++) \
        _Pragma("unroll") \
        for (int h_ = 0; h_ < 2; h_++) { \
            bf16x8 kf = *(const bf16x8*)&smb[sb + (BUF_) * 2048 + (krdL + h_ * 4) * 64 \
                                             + ((((c_ << 2) | quad) ^ ksw) << 3)]; \
            _Pragma("unroll") \
            for (int n_ = 0; n_ < 2; n_++) \
                s[h_][n_] = __builtin_amdgcn_mfma_f32_16x16x32_bf16(kf, bq_[n_][c_], s[h_][n_], 0, 0, 0); \
        } \
    __builtin_amdgcn_s_setprio(0); \
    bf16x8 pb[2]; \
    _Pragma("unroll") \
    for (int n_ = 0; n_ < 2; n_++) { \
        float e0 = __builtin_amdgcn_exp2f(s[0][n_][0]); \
        float e1 = __builtin_amdgcn_exp2f(s[0][n_][1]); \
        float e2 = __builtin_amdgcn_exp2f(s[0][n_][2]); \
        float e3 = __builtin_amdgcn_exp2f(s[0][n_][3]); \
        float e4 = __builtin_amdgcn_exp2f(s[1][n_][0]); \
        float e5 = __builtin_amdgcn_exp2f(s[1][n_][1]); \
        float e6 = __builtin_amdgcn_exp2f(s[1][n_][2]); \
        float e7 = __builtin_amdgcn_exp2f(s[1][n_][3]); \
        pb[n_][0] = (bf16)e0; pb[n_][1] = (bf16)e1; \
        pb[n_][2] = (bf16)e2; pb[n_][3] = (bf16)e3; \
        pb[n_][4] = (bf16)e4; pb[n_][5] = (bf16)e5; \
        pb[n_][6] = (bf16)e6; pb[n_][7] = (bf16)e7; \
        lvs[n_] += ((e0 + e1) + (e2 + e3)) + ((e4 + e5) + (e6 + e7)); \
    } \
    __builtin_amdgcn_s_setprio(1); \
    _Pragma("unroll") \
    for (int t_ = 0; t_ < 4; t_++) { \
        bf16x8 vf = *(const bf16x8*)&smb[sb + 4096 + (BUF_) * 2048 + (t_ * 16 + l16) * 32 + vsw]; \
        _Pragma("unroll") \
        for (int n_ = 0; n_ < 2; n_++) \
            ov[t_][n_] = __builtin_amdgcn_mfma_f32_16x16x32_bf16(vf, pb[n_], ov[t_][n_], 0, 0, 0); \
    } \
    __builtin_amdgcn_s_setprio(0); }

#define SB0 __builtin_amdgcn_sched_barrier(0)

    if (qg == 0) STAGE(0, 0);
#pragma unroll 1
    for (int i = 0; i < 16; i++) {
        if (qg == 0) {
            if (i < 15) {
                STAGE((i + 1) & 1, (i + 1) * 128);
                asm volatile("s_waitcnt vmcnt(8)" ::: "memory");
            } else {
                asm volatile("s_waitcnt vmcnt(0)" ::: "memory");
            }
        }
        SB0;
        __builtin_amdgcn_s_barrier();   // tile i staged data visible
        COMPUTE(i & 1);
        SB0;
        __builtin_amdgcn_s_barrier();   // all reads of buf done before reuse
    }

#undef SB0
#undef COMPUTE
#undef STAGE
#undef GLL

    // ---- cross-slice reduction: partials over ks per (qg, t, n) ----
    // Round A handles d-tiles 0..1, round B 2..3.  8 waves <-> 8 combos
    // (qg x tA x n) per round.  Red 32 KB + Lred 4 KB inside smb.
    f32x4* Red  = (f32x4*)smb;                       // [2qg][2t][2n][4ks][64]
    float* Lred = (float*)((char*)smb + 32768);      // [2qg][2n][4ks][64]
    const int b = bh >> 4, hh = bh & 15;
    const int tA = ks >> 1, nA = ks & 1;

    __syncthreads();
#pragma unroll
    for (int t2 = 0; t2 < 2; t2++)
#pragma unroll
        for (int n = 0; n < 2; n++)
            Red[((((qg * 2 + t2) * 2 + n) * 4) + ks) * 64 + lane] = ov[t2][n];
#pragma unroll
    for (int n = 0; n < 2; n++)
        Lred[((qg * 2 + n) * 4 + ks) * 64 + lane] = lvs[n];
    __syncthreads();

    float ls0 = 0.f, ls1 = 0.f;
#pragma unroll
    for (int k4 = 0; k4 < 4; k4++)
#pragma unroll
        for (int qd = 0; qd < 4; qd++) {
            ls0 += Lred[((qg * 2 + 0) * 4 + k4) * 64 + qd * 16 + l16];
            ls1 += Lred[((qg * 2 + 1) * 4 + k4) * 64 + qd * 16 + l16];
        }
    const float lsn = (ks & 1) ? ls1 : ls0;
    const float iv = 1.0f / lsn;

    {
        f32x4 sv = Red[((((qg * 2 + tA) * 2 + nA) * 4) + 0) * 64 + lane]
                 + Red[((((qg * 2 + tA) * 2 + nA) * 4) + 1) * 64 + lane]
                 + Red[((((qg * 2 + tA) * 2 + nA) * 4) + 2) * 64 + lane]
                 + Red[((((qg * 2 + tA) * 2 + nA) * 4) + 3) * 64 + lane];
        bf16x4 ob = {(bf16)(sv[0] * iv), (bf16)(sv[1] * iv),
                     (bf16)(sv[2] * iv), (bf16)(sv[3] * iv)};
        size_t off = ((size_t)(b * SEQ + q0 + qg * 32 + nA * 16 + l16)) * D_MODEL
                   + hh * 64 + tA * 16 + quad * 4;
        *(bf16x4*)&ctx[off] = ob;
    }
    __syncthreads();
#pragma unroll
    for (int t2 = 0; t2 < 2; t2++)
#pragma unroll
        for (int n = 0; n < 2; n++)
            Red[((((qg * 2 + t2) * 2 + n) * 4) + ks) * 64 + lane] = ov[2 + t2][n];
    __syncthreads();
    {
        f32x4 sv = Red[((((qg * 2 + tA) * 2 + nA) * 4) + 0) * 64 + lane]
                 + Red[((((qg * 2 + tA) * 2 + nA) * 4) + 1) * 64 + lane]
                 + Red[((((qg * 2 + tA) * 2 + nA) * 4) + 2) * 64 + lane]
                 + Red[((((qg * 2 + tA) * 2 + nA) * 4) + 3) * 64 + lane];
        bf16x4 ob = {(bf16)(sv[0] * iv), (bf16)(sv[1] * iv),
                     (bf16)(sv[2] * iv), (bf16)(sv[3] * iv)};
        size_t off = ((size_t)(b * SEQ + q0 + qg * 32 + nA * 16 + l16)) * D_MODEL
                   + hh * 64 + (2 + tA) * 16 + quad * 4;
        *(bf16x4*)&ctx[off] = ob;
    }
}

// ---------------------------------------------------------------------------
// Kernel 4: output projection (R6-measured version, unchanged).
// ---------------------------------------------------------------------------
__global__ __launch_bounds__(256) void out_gemm(const bf16* __restrict__ ctx,
                                                const bf16* __restrict__ wot,
                                                const float* __restrict__ bo,
                                                float* __restrict__ out) {
    __shared__ bf16 As[64 * 32];
    __shared__ bf16 Bs[128 * 32];
    const int tid = threadIdx.x;
    const int lane = tid & 63, wave = tid >> 6;
    const int quad = lane >> 4, l16 = lane & 15;
    const int srow = lane >> 2, selem = (lane & 3) * 8;
    int row0 = blockIdx.y * 64, col0 = blockIdx.x * 128;
    f32x4 acc[4][2] = {};

    for (int k0 = 0; k0 < D_MODEL; k0 += 32) {
        __syncthreads();
        {
            const bf16* ga = ctx + (size_t)(row0 + wave * 16 + srow) * D_MODEL + k0 + selem;
            __builtin_amdgcn_global_load_lds((gbl_void*)ga, (lds_void*)(As + wave * 512 + lane * 8), 16, 0, 0);
        }
#pragma unroll
        for (int t = 0; t < 2; t++) {
            int m = wave * 2 + t;
            const bf16* gb = wot + (size_t)(col0 + m * 16 + srow) * D_MODEL + k0 + selem;
            __builtin_amdgcn_global_load_lds((gbl_void*)gb, (lds_void*)(Bs + m * 512 + lane * 8), 16, 0, 0);
        }
        __syncthreads();
        bf16x8 af[4], bfr[2];
#pragma unroll
        for (int i = 0; i < 4; i++)
            af[i] = *(const bf16x8*)&As[(i * 16 + l16) * 32 + quad * 8];
#pragma unroll
        for (int j = 0; j < 2; j++)
            bfr[j] = *(const bf16x8*)&Bs[(wave * 32 + j * 16 + l16) * 32 + quad * 8];
#pragma unroll
        for (int i = 0; i < 4; i++)
#pragma unroll
            for (int j = 0; j < 2; j++)
                acc[i][j] = __builtin_amdgcn_mfma_f32_16x16x32_bf16(af[i], bfr[j], acc[i][j], 0, 0, 0);
    }
#pragma unroll
    for (int i = 0; i < 4; i++)
#pragma unroll
        for (int j = 0; j < 2; j++) {
            int colg = col0 + wave * 32 + j * 16 + l16;
            float bi = bo[colg];
            int rbase = row0 + i * 16 + quad * 4;
#pragma unroll
            for (int r = 0; r < 4; r++)
                out[(size_t)(rbase + r) * D_MODEL + colg] = acc[i][j][r] + bi;
        }
}

// ---------------------------------------------------------------------------
extern "C" void kernel_launch(void* const* d_in, const int* in_sizes, int n_in,
                              void* d_out, int out_size, void* d_ws, size_t ws_size,
                              hipStream_t stream) {
    const float* x  = (const float*)d_in[0];
    const float* wq = (const float*)d_in[1];
    const float* bq = (const float*)d_in[2];
    const float* wk = (const float*)d_in[3];
    const float* bk = (const float*)d_in[4];
    const float* wv = (const float*)d_in[5];
    const float* bv = (const float*)d_in[6];
    const float* wo = (const float*)d_in[7];
    const float* bo = (const float*)d_in[8];
    float* out = (float*)d_out;

    const size_t MB = 1024 * 1024;
    char* ws = (char*)d_ws;
    bf16* xb  = (bf16*)(ws);             // [4096][1024]            8 MB
    bf16* wtb = (bf16*)(ws + 8 * MB);    // [4][1024][1024] (N,K)   8 MB
    bf16* qb  = (bf16*)(ws + 16 * MB);   // [B,H,S,64] (scaled)     8 MB
    bf16* kb  = (bf16*)(ws + 24 * MB);   // [B,H,S,64]              8 MB
    bf16* vb  = (bf16*)(ws + 32 * MB);   // [B,H,64,S]              8 MB
    bf16* ctx = (bf16*)(ws + 40 * MB);   // [4096][1024]            8 MB

    prep<<<dim3(32, 32, 8), dim3(32, 8), 0, stream>>>(wq, wk, wv, wo, x, wtb, xb);
    qkv_gemm<<<dim3(192), dim3(512), 0, stream>>>(xb, wtb, bq, bk, bv, qb, kb, vb);
    attn<<<dim3(BATCH * NHEAD, SEQ / 64), dim3(512), 0, stream>>>(qb, kb, vb, ctx);
    out_gemm<<<dim3(8, 64), 256, 0, stream>>>(ctx, wtb + 3 * (size_t)D_MODEL * D_MODEL, bo, out);
}

// Round 10
// 189.479 us; speedup vs baseline: 1.0085x; 1.0079x over previous
//
#include <hip/hip_runtime.h>
#include <hip/hip_bf16.h>

typedef __bf16 bf16;
typedef __bf16 bf16x4 __attribute__((ext_vector_type(4)));
typedef __bf16 bf16x8 __attribute__((ext_vector_type(8)));
typedef float f32x4 __attribute__((ext_vector_type(4)));

typedef __attribute__((address_space(3))) void lds_void;
typedef const __attribute__((address_space(1))) void gbl_void;

#define D_MODEL 1024
#define NHEAD 16
#define DEPTH 64
#define SEQ 2048
#define BATCH 2
#define NTOK (BATCH * SEQ)   // 4096

// 1/sqrt(64) * log2(e): folded into q so attention exp is a bare exp2.
#define Q_SCALE 0.18033688f

// ---------------------------------------------------------------------------
// Kernel 1: prep = weight transpose+convert (z=0..3) + x convert (z=4..7).
// ---------------------------------------------------------------------------
__global__ __launch_bounds__(256) void prep(const float* __restrict__ w0,
                                            const float* __restrict__ w1,
                                            const float* __restrict__ w2,
                                            const float* __restrict__ w3,
                                            const float* __restrict__ x,
                                            bf16* __restrict__ wtb,
                                            bf16* __restrict__ xb) {
    int z = blockIdx.z;
    int tx = threadIdx.x, ty = threadIdx.y;   // (32, 8)
    if (z < 4) {
        const float* w = (z == 0) ? w0 : (z == 1) ? w1 : (z == 2) ? w2 : w3;
        bf16* d = wtb + (size_t)z * D_MODEL * D_MODEL;
        __shared__ float tile[32][33];
        int c0 = blockIdx.x * 32;   // source col block (n)
        int r0 = blockIdx.y * 32;   // source row block (k)
#pragma unroll
        for (int i = 0; i < 4; i++)
            tile[ty + i * 8][tx] = w[(size_t)(r0 + ty + i * 8) * D_MODEL + c0 + tx];
        __syncthreads();
#pragma unroll
        for (int i = 0; i < 4; i++)
            d[(size_t)(c0 + ty + i * 8) * D_MODEL + r0 + tx] = (bf16)tile[tx][ty + i * 8];
    } else {
        int t = ty * 32 + tx;
        size_t i = ((size_t)(z - 4) * 1024 + blockIdx.y * 32 + blockIdx.x) * 256 + t;
        float4 v = ((const float4*)x)[i];
        bf16x4 o = {(bf16)v.x, (bf16)v.y, (bf16)v.z, (bf16)v.w};
        *(bf16x4*)&xb[i * 4] = o;
    }
}

// ---------------------------------------------------------------------------
// Kernel 2: QKV projection, 256x256 tile, BK=64, 8 waves, 8-phase counted
// vmcnt schedule (unchanged this round).
// ---------------------------------------------------------------------------
__global__ __launch_bounds__(512, 2) void qkv_gemm(const bf16* __restrict__ xb,
                                                   const bf16* __restrict__ wtb,
                                                   const float* __restrict__ bq,
                                                   const float* __restrict__ bk,
                                                   const float* __restrict__ bv,
                                                   bf16* __restrict__ q,
                                                   bf16* __restrict__ k,
                                                   bf16* __restrict__ v) {
    __shared__ bf16 sm[65536];   // 128 KiB

    const int flat = blockIdx.x;
    const int wg = (flat & 7) * 24 + (flat >> 3);
    const int mt = wg & 15, nt = wg >> 4;     // wg = nt*16 + mt
    const int row0 = mt << 8;                 // token base
    const int z = nt >> 2;                    // 0=q 1=k 2=v
    const int nb = (nt & 3) << 8;             // feature base within z

    const int tid = threadIdx.x;
    const int lane = tid & 63, wave = tid >> 6;
    const int wm = wave >> 2, wn = wave & 3;  // 2 x 4 wave grid
    const int quad = lane >> 4, l16 = lane & 15;
    const int kch = ((quad ^ ((l16 >> 1) & 3)) << 3);   // swizzled 16B chunk (elems)

    const int srow = lane >> 2;
    const int scg = (lane & 3) ^ ((lane >> 3) & 3);     // pre-swizzled src chunk
    const int stDst = wave * 1024 + lane * 8;           // elems within half

    const bf16* Ag = xb + (size_t)(row0 + wave * 32 + srow) * D_MODEL + scg * 8;
    const bf16* Bg = wtb + (size_t)z * D_MODEL * D_MODEL
                   + (size_t)(nb + wave * 32 + srow) * D_MODEL + scg * 8;

    f32x4 acc[8][4] = {};
    bf16x8 bfr[4];

#define GLL(SRC, DST) __builtin_amdgcn_global_load_lds((gbl_void*)(SRC), (lds_void*)(DST), 16, 0, 0)
#define STG_A(T_, KQ_, BUF_) { \
    const bf16* s_ = Ag + (T_) * 64 + (KQ_) * 32; \
    bf16* d_ = sm + (BUF_) * 16384 + (KQ_) * 8192 + stDst; \
    GLL(s_, d_); GLL(s_ + 16 * D_MODEL, d_ + 512); }
#define STG_B(T_, KQ_, BUF_) { \
    const bf16* s_ = Bg + (T_) * 64 + (KQ_) * 32; \
    bf16* d_ = sm + 32768 + (BUF_) * 16384 + (KQ_) * 8192 + stDst; \
    GLL(s_, d_); GLL(s_ + 16 * D_MODEL, d_ + 512); }
#define WAIT6 { asm volatile("s_waitcnt vmcnt(6)" ::: "memory"); }
#define NOW

#define PHASE(BUF_, KQ_, MQ_, STG_STMT, WAIT_STMT) { \
    bf16x8 af[4]; \
    const int ab_ = (BUF_) * 16384 + (KQ_) * 8192 + (wm * 128 + (MQ_) * 64 + l16) * 32 + kch; \
    _Pragma("unroll") \
    for (int i_ = 0; i_ < 4; i_++) af[i_] = *(const bf16x8*)&sm[ab_ + i_ * 512]; \
    if ((MQ_) == 0) { \
        const int bb_ = 32768 + (BUF_) * 16384 + (KQ_) * 8192 + (wn * 64 + l16) * 32 + kch; \
        _Pragma("unroll") \
        for (int j_ = 0; j_ < 4; j_++) bfr[j_] = *(const bf16x8*)&sm[bb_ + j_ * 512]; \
    } \
    STG_STMT; \
    WAIT_STMT; \
    __builtin_amdgcn_sched_barrier(0); \
    __builtin_amdgcn_s_barrier(); \
    __builtin_amdgcn_s_setprio(1); \
    _Pragma("unroll") \
    for (int i_ = 0; i_ < 4; i_++) \
        _Pragma("unroll") \
        for (int j_ = 0; j_ < 4; j_++) \
            acc[(MQ_) * 4 + i_][j_] = __builtin_amdgcn_mfma_f32_16x16x32_bf16( \
                af[i_], bfr[j_], acc[(MQ_) * 4 + i_][j_], 0, 0, 0); \
    __builtin_amdgcn_s_setprio(0); \
    __builtin_amdgcn_sched_barrier(0); \
    __builtin_amdgcn_s_barrier(); }

    STG_B(0, 0, 0);
    STG_A(0, 0, 0);
    STG_B(0, 1, 0);
    STG_A(0, 1, 0);
    asm volatile("s_waitcnt vmcnt(4)" ::: "memory");
    STG_B(1, 0, 1);
    STG_A(1, 0, 1);
    STG_B(1, 1, 1);
    asm volatile("s_waitcnt vmcnt(6)" ::: "memory");
    __builtin_amdgcn_sched_barrier(0);
    __builtin_amdgcn_s_barrier();

#pragma unroll 1
    for (int it = 0; it < 8; ++it) {
        const int t1 = 2 * it + 1;
        const int t2 = (2 * it + 2) & 15;   // wrap keeps vmcnt counts exact at tail
        const int t3 = (2 * it + 3) & 15;
        PHASE(0, 0, 0, STG_A(t1, 1, 1), NOW)      // ph1
        PHASE(0, 0, 1, STG_B(t2, 0, 0), NOW)      // ph2
        PHASE(0, 1, 0, STG_A(t2, 0, 0), NOW)      // ph3
        PHASE(0, 1, 1, STG_B(t2, 1, 0), WAIT6)    // ph4
        PHASE(1, 0, 0, STG_A(t2, 1, 0), NOW)      // ph5
        PHASE(1, 0, 1, STG_B(t3, 0, 1), NOW)      // ph6
        PHASE(1, 1, 0, STG_A(t3, 0, 1), NOW)      // ph7
        PHASE(1, 1, 1, STG_B(t3, 1, 1), WAIT6)    // ph8
    }

#undef PHASE
#undef WAIT6
#undef NOW
#undef STG_A
#undef STG_B
#undef GLL

    const float* bias = (z == 0) ? bq : (z == 1) ? bk : bv;
    const int bI = row0 >> 11;
    const int sBase = row0 & 2047;
    if (z < 2) {
        bf16* dst = (z == 0) ? q : k;   // [B,H,S,64]
        const float scl = (z == 0) ? Q_SCALE : 1.0f;
#pragma unroll
        for (int j = 0; j < 4; j++) {
            const int f = nb + wn * 64 + j * 16 + l16;
            const float bi = bias[f];
            const int hh = f >> 6, d = f & 63;
            bf16* dcol = dst + ((size_t)(bI * NHEAD + hh) * SEQ) * DEPTH + d;
#pragma unroll
            for (int mi = 0; mi < 8; mi++) {
                const int s0 = sBase + wm * 128 + (mi >> 2) * 64 + (mi & 3) * 16 + quad * 4;
#pragma unroll
                for (int r = 0; r < 4; r++)
                    dcol[(size_t)(s0 + r) * DEPTH] = (bf16)((acc[mi][j][r] + bi) * scl);
            }
        }
    } else {
#pragma unroll
        for (int j = 0; j < 4; j++) {
            const int f = nb + wn * 64 + j * 16 + l16;
            const float bi = bias[f];
            const int hh = f >> 6, d = f & 63;
            bf16* vrow = v + ((size_t)(bI * NHEAD + hh) * DEPTH + d) * SEQ;
#pragma unroll
            for (int mi = 0; mi < 8; mi++) {
                const int s0 = sBase + wm * 128 + (mi >> 2) * 64 + (mi & 3) * 16 + quad * 4;
                f32x4 a = acc[mi][j];
                bf16x4 ob = {(bf16)(a[0] + bi), (bf16)(a[1] + bi),
                             (bf16)(a[2] + bi), (bf16)(a[3] + bi)};
                *(bf16x4*)&vrow[s0] = ob;
            }
        }
    }
}

// ---------------------------------------------------------------------------
// Kernel 3: flash attention, R13 = R12 with the V bank-conflict FIX.
// R12 audit: V fragment reads (64B rows, bank = (row&1)*16 + chunk*4) with
// swizzle s(d)=d&3 put consecutive 8-lane groups on only 4 of 8
// (parity,chunk) slots -> structural 2-way+ conflict on every V read
// (the 4.2M SQ_LDS_BANK_CONFLICT).  New generator s(d) = (d>>1)&3 makes
// each 8-lane group hit 8 distinct slots (audited lane-by-lane).  Both
// sides changed together (G21): staging source chunk (lane&3)^((lane>>3)&3),
// read chunk quad^((l16>>1)&3).  K reads audited clean (unchanged).
// Everything else identical to R12.
// ---------------------------------------------------------------------------
__global__ __launch_bounds__(512, 4) void attn(const bf16* __restrict__ q,
                                               const bf16* __restrict__ k,
                                               const bf16* __restrict__ v,
                                               bf16* __restrict__ ctx) {
    __shared__ __align__(16) bf16 smb[32768];   // 64 KB: 4 slices x 16 KB
    const int tid = threadIdx.x;
    const int lane = tid & 63, wave = tid >> 6;   // 8 waves
    const int ks = wave & 3, qg = wave >> 2;
    const int quad = lane >> 4, l16 = lane & 15;
    const int bh = blockIdx.x;
    const int q0 = blockIdx.y * 64;
    const size_t hb = (size_t)bh * SEQ * DEPTH;
    const bf16* qh = q + hb;
    const bf16* kh = k + hb;            // [S][64]
    const bf16* vh = v + hb;            // [64][S]

    // Q as B-fragments: this wave's 32 q rows (qg half)
    bf16x8 bq_[2][2];
#pragma unroll
    for (int n = 0; n < 2; n++) {
        int qrow = q0 + qg * 32 + n * 16 + l16;
#pragma unroll
        for (int c = 0; c < 2; c++)
            bq_[n][c] = *(const bf16x8*)&qh[(size_t)qrow * DEPTH + c * 32 + quad * 8];
    }

    f32x4 ov[4][2] = {};        // [d-tile][q-tile] kv-partial ctx^T
    float lvs[2] = {0.f, 0.f};  // [q-tile] quad-partial row sums

    // slice LDS base (elems): K at sb + buf*2048, V at sb + 4096 + buf*2048
    const int sb = ks * 8192;
    // staging source swizzles (used by qg==0 only)
    const int kchS = (lane & 7) ^ (((lane >> 3) & 3) << 1);   // ^ (o&1) per o
    const int vchS = (lane & 3) ^ ((lane >> 3) & 3);          // s(d) = (d>>1)&3
    // fragment-read geometry
    const int krdL = ((l16 >> 2) << 3) + (l16 & 3);           // local row, + h*4
    const int ksw = ((l16 & 3) << 1) | ((l16 >> 2) & 1);      // = s(row)
    const int vsw = (quad ^ ((l16 >> 1) & 3)) << 3;           // V read chunk

#define GLL(SRC, DST) __builtin_amdgcn_global_load_lds((gbl_void*)(SRC), (lds_void*)(DST), 16, 0, 0)

#define STAGE(BUF_, T_) { \
    _Pragma("unroll") \
    for (int o_ = 0; o_ < 4; o_++) { \
        const bf16* s_ = kh + (size_t)((T_) + ks * 32 + o_ * 8 + (lane >> 3)) * DEPTH \
                       + ((kchS ^ (o_ & 1)) << 3); \
        GLL(s_, smb + sb + (BUF_) * 2048 + o_ * 512 + lane * 8); \
    } \
    _Pragma("unroll") \
    for (int o_ = 0; o_ < 4; o_++) { \
        const bf16* s_ = vh + (size_t)(o_ * 16 + (lane >> 2)) * SEQ + (T_) + ks * 32 \
                       + (vchS << 3); \
        GLL(s_, smb + sb + 4096 + (BUF_) * 2048 + o_ * 512 + lane * 8); \
    } }

#define COMPUTE(BUF_) { \
    f32x4 s[2][2] = {}; \
    __builtin_amdgcn_s_setprio(1); \
    _Pragma("unroll") \
    for (int c_ = 0; c_ < 2; c_++) \
        _Pragma("unroll") \
        for (int h_ = 0; h_ < 2; h_++) { \
            bf16x8 kf = *(const bf16x8*)&smb[sb + (BUF_) * 2048 + (krdL + h_ * 4) * 64 \
                                             + ((((c_ << 2) | quad) ^ ksw) << 3)]; \
            _Pragma("unroll") \
            for (int n_ = 0; n_ < 2; n_++) \
                s[h_][n_] = __builtin_amdgcn_mfma_f32_16x16x32_bf16(kf, bq_[n_][c_], s[h_][n_], 0, 0, 0); \
        } \
    __builtin_amdgcn_s_setprio(0); \
    bf16x8 pb[2]; \
    _Pragma("unroll") \
    for (int n_ = 0; n_ < 2; n_++) { \
        float e0 = __builtin_amdgcn_exp2f(s[0][n_][0]); \
        float e1 = __builtin_amdgcn_exp2f(s[0][n_][1]); \
        float e2 = __builtin_amdgcn_exp2f(s[0][n_][2]); \
        float e3 = __builtin_amdgcn_exp2f(s[0][n_][3]); \
        float e4 = __builtin_amdgcn_exp2f(s[1][n_][0]); \
        float e5 = __builtin_amdgcn_exp2f(s[1][n_][1]); \
        float e6 = __builtin_amdgcn_exp2f(s[1][n_][2]); \
        float e7 = __builtin_amdgcn_exp2f(s[1][n_][3]); \
        pb[n_][0] = (bf16)e0; pb[n_][1] = (bf16)e1; \
        pb[n_][2] = (bf16)e2; pb[n_][3] = (bf16)e3; \
        pb[n_][4] = (bf16)e4; pb[n_][5] = (bf16)e5; \
        pb[n_][6] = (bf16)e6; pb[n_][7] = (bf16)e7; \
        lvs[n_] += ((e0 + e1) + (e2 + e3)) + ((e4 + e5) + (e6 + e7)); \
    } \
    __builtin_amdgcn_s_setprio(1); \
    _Pragma("unroll") \
    for (int t_ = 0; t_ < 4; t_++) { \
        bf16x8 vf = *(const bf16x8*)&smb[sb + 4096 + (BUF_) * 2048 + (t_ * 16 + l16) * 32 + vsw]; \
        _Pragma("unroll") \
        for (int n_ = 0; n_ < 2; n_++) \
            ov[t_][n_] = __builtin_amdgcn_mfma_f32_16x16x32_bf16(vf, pb[n_], ov[t_][n_], 0, 0, 0); \
    } \
    __builtin_amdgcn_s_setprio(0); }

#define SB0 __builtin_amdgcn_sched_barrier(0)

    if (qg == 0) STAGE(0, 0);
#pragma unroll 1
    for (int i = 0; i < 16; i++) {
        if (qg == 0) {
            if (i < 15) {
                STAGE((i + 1) & 1, (i + 1) * 128);
                asm volatile("s_waitcnt vmcnt(8)" ::: "memory");
            } else {
                asm volatile("s_waitcnt vmcnt(0)" ::: "memory");
            }
        }
        SB0;
        __builtin_amdgcn_s_barrier();   // tile i staged data visible
        COMPUTE(i & 1);
        SB0;
        __builtin_amdgcn_s_barrier();   // all reads of buf done before reuse
    }

#undef SB0
#undef COMPUTE
#undef STAGE
#undef GLL

    // ---- cross-slice reduction: partials over ks per (qg, t, n) ----
    f32x4* Red  = (f32x4*)smb;                       // [2qg][2t][2n][4ks][64]
    float* Lred = (float*)((char*)smb + 32768);      // [2qg][2n][4ks][64]
    const int b = bh >> 4, hh = bh & 15;
    const int tA = ks >> 1, nA = ks & 1;

    __syncthreads();
#pragma unroll
    for (int t2 = 0; t2 < 2; t2++)
#pragma unroll
        for (int n = 0; n < 2; n++)
            Red[((((qg * 2 + t2) * 2 + n) * 4) + ks) * 64 + lane] = ov[t2][n];
#pragma unroll
    for (int n = 0; n < 2; n++)
        Lred[((qg * 2 + n) * 4 + ks) * 64 + lane] = lvs[n];
    __syncthreads();

    float ls0 = 0.f, ls1 = 0.f;
#pragma unroll
    for (int k4 = 0; k4 < 4; k4++)
#pragma unroll
        for (int qd = 0; qd < 4; qd++) {
            ls0 += Lred[((qg * 2 + 0) * 4 + k4) * 64 + qd * 16 + l16];
            ls1 += Lred[((qg * 2 + 1) * 4 + k4) * 64 + qd * 16 + l16];
        }
    const float lsn = (ks & 1) ? ls1 : ls0;
    const float iv = 1.0f / lsn;

    {
        f32x4 sv = Red[((((qg * 2 + tA) * 2 + nA) * 4) + 0) * 64 + lane]
                 + Red[((((qg * 2 + tA) * 2 + nA) * 4) + 1) * 64 + lane]
                 + Red[((((qg * 2 + tA) * 2 + nA) * 4) + 2) * 64 + lane]
                 + Red[((((qg * 2 + tA) * 2 + nA) * 4) + 3) * 64 + lane];
        bf16x4 ob = {(bf16)(sv[0] * iv), (bf16)(sv[1] * iv),
                     (bf16)(sv[2] * iv), (bf16)(sv[3] * iv)};
        size_t off = ((size_t)(b * SEQ + q0 + qg * 32 + nA * 16 + l16)) * D_MODEL
                   + hh * 64 + tA * 16 + quad * 4;
        *(bf16x4*)&ctx[off] = ob;
    }
    __syncthreads();
#pragma unroll
    for (int t2 = 0; t2 < 2; t2++)
#pragma unroll
        for (int n = 0; n < 2; n++)
            Red[((((qg * 2 + t2) * 2 + n) * 4) + ks) * 64 + lane] = ov[2 + t2][n];
    __syncthreads();
    {
        f32x4 sv = Red[((((qg * 2 + tA) * 2 + nA) * 4) + 0) * 64 + lane]
                 + Red[((((qg * 2 + tA) * 2 + nA) * 4) + 1) * 64 + lane]
                 + Red[((((qg * 2 + tA) * 2 + nA) * 4) + 2) * 64 + lane]
                 + Red[((((qg * 2 + tA) * 2 + nA) * 4) + 3) * 64 + lane];
        bf16x4 ob = {(bf16)(sv[0] * iv), (bf16)(sv[1] * iv),
                     (bf16)(sv[2] * iv), (bf16)(sv[3] * iv)};
        size_t off = ((size_t)(b * SEQ + q0 + qg * 32 + nA * 16 + l16)) * D_MODEL
                   + hh * 64 + (2 + tA) * 16 + quad * 4;
        *(bf16x4*)&ctx[off] = ob;
    }
}

// ---------------------------------------------------------------------------
// Kernel 4: output projection (R6-measured version, unchanged).
// ---------------------------------------------------------------------------
__global__ __launch_bounds__(256) void out_gemm(const bf16* __restrict__ ctx,
                                                const bf16* __restrict__ wot,
                                                const float* __restrict__ bo,
                                                float* __restrict__ out) {
    __shared__ bf16 As[64 * 32];
    __shared__ bf16 Bs[128 * 32];
    const int tid = threadIdx.x;
    const int lane = tid & 63, wave = tid >> 6;
    const int quad = lane >> 4, l16 = lane & 15;
    const int srow = lane >> 2, selem = (lane & 3) * 8;
    int row0 = blockIdx.y * 64, col0 = blockIdx.x * 128;
    f32x4 acc[4][2] = {};

    for (int k0 = 0; k0 < D_MODEL; k0 += 32) {
        __syncthreads();
        {
            const bf16* ga = ctx + (size_t)(row0 + wave * 16 + srow) * D_MODEL + k0 + selem;
            __builtin_amdgcn_global_load_lds((gbl_void*)ga, (lds_void*)(As + wave * 512 + lane * 8), 16, 0, 0);
        }
#pragma unroll
        for (int t = 0; t < 2; t++) {
            int m = wave * 2 + t;
            const bf16* gb = wot + (size_t)(col0 + m * 16 + srow) * D_MODEL + k0 + selem;
            __builtin_amdgcn_global_load_lds((gbl_void*)gb, (lds_void*)(Bs + m * 512 + lane * 8), 16, 0, 0);
        }
        __syncthreads();
        bf16x8 af[4], bfr[2];
#pragma unroll
        for (int i = 0; i < 4; i++)
            af[i] = *(const bf16x8*)&As[(i * 16 + l16) * 32 + quad * 8];
#pragma unroll
        for (int j = 0; j < 2; j++)
            bfr[j] = *(const bf16x8*)&Bs[(wave * 32 + j * 16 + l16) * 32 + quad * 8];
#pragma unroll
        for (int i = 0; i < 4; i++)
#pragma unroll
            for (int j = 0; j < 2; j++)
                acc[i][j] = __builtin_amdgcn_mfma_f32_16x16x32_bf16(af[i], bfr[j], acc[i][j], 0, 0, 0);
    }
#pragma unroll
    for (int i = 0; i < 4; i++)
#pragma unroll
        for (int j = 0; j < 2; j++) {
            int colg = col0 + wave * 32 + j * 16 + l16;
            float bi = bo[colg];
            int rbase = row0 + i * 16 + quad * 4;
#pragma unroll
            for (int r = 0; r < 4; r++)
                out[(size_t)(rbase + r) * D_MODEL + colg] = acc[i][j][r] + bi;
        }
}

// ---------------------------------------------------------------------------
extern "C" void kernel_launch(void* const* d_in, const int* in_sizes, int n_in,
                              void* d_out, int out_size, void* d_ws, size_t ws_size,
                              hipStream_t stream) {
    const float* x  = (const float*)d_in[0];
    const float* wq = (const float*)d_in[1];
    const float* bq = (const float*)d_in[2];
    const float* wk = (const float*)d_in[3];
    const float* bk = (const float*)d_in[4];
    const float* wv = (const float*)d_in[5];
    const float* bv = (const float*)d_in[6];
    const float* wo = (const float*)d_in[7];
    const float* bo = (const float*)d_in[8];
    float* out = (float*)d_out;

    const size_t MB = 1024 * 1024;
    char* ws = (char*)d_ws;
    bf16* xb  = (bf16*)(ws);             // [4096][1024]            8 MB
    bf16* wtb = (bf16*)(ws + 8 * MB);    // [4][1024][1024] (N,K)   8 MB
    bf16* qb  = (bf16*)(ws + 16 * MB);   // [B,H,S,64] (scaled)     8 MB
    bf16* kb  = (bf16*)(ws + 24 * MB);   // [B,H,S,64]              8 MB
    bf16* vb  = (bf16*)(ws + 32 * MB);   // [B,H,64,S]              8 MB
    bf16* ctx = (bf16*)(ws + 40 * MB);   // [4096][1024]            8 MB

    prep<<<dim3(32, 32, 8), dim3(32, 8), 0, stream>>>(wq, wk, wv, wo, x, wtb, xb);
    qkv_gemm<<<dim3(192), dim3(512), 0, stream>>>(xb, wtb, bq, bk, bv, qb, kb, vb);
    attn<<<dim3(BATCH * NHEAD, SEQ / 64), dim3(512), 0, stream>>>(qb, kb, vb, ctx);
    out_gemm<<<dim3(8, 64), 256, 0, stream>>>(ctx, wtb + 3 * (size_t)D_MODEL * D_MODEL, bo, out);
}

// Round 11
// 182.597 us; speedup vs baseline: 1.0465x; 1.0377x over previous
//
#include <hip/hip_runtime.h>
#include <hip/hip_bf16.h>

typedef __bf16 bf16;
typedef __bf16 bf16x4 __attribute__((ext_vector_type(4)));
typedef __bf16 bf16x8 __attribute__((ext_vector_type(8)));
typedef float f32x4 __attribute__((ext_vector_type(4)));

typedef __attribute__((address_space(3))) void lds_void;
typedef const __attribute__((address_space(1))) void gbl_void;

#define D_MODEL 1024
#define NHEAD 16
#define DEPTH 64
#define SEQ 2048
#define BATCH 2
#define NTOK (BATCH * SEQ)   // 4096

// 1/sqrt(64) * log2(e): folded into q so attention exp is a bare exp2.
#define Q_SCALE 0.18033688f

// ---------------------------------------------------------------------------
// Kernel 1: prep = weight transpose+convert (z=0..3) + x convert (z=4..7).
// ---------------------------------------------------------------------------
__global__ __launch_bounds__(256) void prep(const float* __restrict__ w0,
                                            const float* __restrict__ w1,
                                            const float* __restrict__ w2,
                                            const float* __restrict__ w3,
                                            const float* __restrict__ x,
                                            bf16* __restrict__ wtb,
                                            bf16* __restrict__ xb) {
    int z = blockIdx.z;
    int tx = threadIdx.x, ty = threadIdx.y;   // (32, 8)
    if (z < 4) {
        const float* w = (z == 0) ? w0 : (z == 1) ? w1 : (z == 2) ? w2 : w3;
        bf16* d = wtb + (size_t)z * D_MODEL * D_MODEL;
        __shared__ float tile[32][33];
        int c0 = blockIdx.x * 32;   // source col block (n)
        int r0 = blockIdx.y * 32;   // source row block (k)
#pragma unroll
        for (int i = 0; i < 4; i++)
            tile[ty + i * 8][tx] = w[(size_t)(r0 + ty + i * 8) * D_MODEL + c0 + tx];
        __syncthreads();
#pragma unroll
        for (int i = 0; i < 4; i++)
            d[(size_t)(c0 + ty + i * 8) * D_MODEL + r0 + tx] = (bf16)tile[tx][ty + i * 8];
    } else {
        int t = ty * 32 + tx;
        size_t i = ((size_t)(z - 4) * 1024 + blockIdx.y * 32 + blockIdx.x) * 256 + t;
        float4 v = ((const float4*)x)[i];
        bf16x4 o = {(bf16)v.x, (bf16)v.y, (bf16)v.z, (bf16)v.w};
        *(bf16x4*)&xb[i * 4] = o;
    }
}

// ---------------------------------------------------------------------------
// Kernel 2: QKV projection, R14 rewrite: 128x128 tiles, BK=64, 16 K-tiles,
// double-buffered 64 KiB LDS, counted vmcnt(8) (the session-verified R6-attn
// 2-phase pattern: stage next -> vmcnt(8) -> barrier -> compute -> barrier,
// never vmcnt(0) in the loop).  Grid (24,32) = 768 blocks = 3 blocks/CU
// (100% CU coverage vs R1's 75%), 2 resident/CU (64 KiB LDS) de-phasing
// each other.  Conflict-free chunk swizzle: 128B rows (bank-period) would
// make every 8-lane group hit one 16B chunk slot (8-way); storing chunk c
// of row r at physical p = c ^ (r&7) spreads each 8-lane group over 8
// distinct slots (2 lanes/slot over 16 lanes = free).  Staged via
// pre-swizzled SOURCE chunk (G21; LDS dst linear for global_load_lds).
// Epilogue: R0's harness-verified acc[4][4] scatter, verbatim.
// XCD: blockIdx.x = zc (z=zc>>3, col=zc&7) -> XCD = col -> each weight
// col-tile pinned to one XCD's L2 (as in R0).
// ---------------------------------------------------------------------------
template <bool SWAP>
__device__ __forceinline__ void gemm_core128(const bf16* __restrict__ A,
                                             const bf16* __restrict__ Bt,
                                             int row0, int col0,
                                             bf16 (*sm)[2][8192],
                                             f32x4 acc[4][4]) {
    const int tid = threadIdx.x;
    const int lane = tid & 63;
    const int wave = tid >> 6;
    const int quad = lane >> 4, l16 = lane & 15;
    const int wm = (wave & 1) << 6, wn = (wave >> 1) << 6;
    const int sA = l16 & 7;                      // read-side swizzle key
    const int scg = (tid & 7) ^ ((tid >> 3) & 7);   // pre-swizzled src chunk

    const bf16* Ag = A + (size_t)(row0 + (tid >> 3)) * D_MODEL + scg * 8;
    const bf16* Bg = Bt + (size_t)(col0 + (tid >> 3)) * D_MODEL + scg * 8;

#define GLLQ(SRC, DST) __builtin_amdgcn_global_load_lds((gbl_void*)(SRC), (lds_void*)(DST), 16, 0, 0)
#define STGQ(BUF_, KB_) { \
    _Pragma("unroll") \
    for (int o_ = 0; o_ < 4; o_++) \
        GLLQ(Ag + (size_t)o_ * 32 * D_MODEL + (KB_), &sm[BUF_][0][o_ * 2048 + tid * 8]); \
    _Pragma("unroll") \
    for (int o_ = 0; o_ < 4; o_++) \
        GLLQ(Bg + (size_t)o_ * 32 * D_MODEL + (KB_), &sm[BUF_][1][o_ * 2048 + tid * 8]); }

    STGQ(0, 0);
#pragma unroll 1
    for (int t = 0; t < 16; t++) {
        if (t < 15) {
            STGQ((t + 1) & 1, (t + 1) * 64);
            asm volatile("s_waitcnt vmcnt(8)" ::: "memory");
        } else {
            asm volatile("s_waitcnt vmcnt(0)" ::: "memory");
        }
        __builtin_amdgcn_sched_barrier(0);
        __builtin_amdgcn_s_barrier();
        const int bs = t & 1;
#pragma unroll
        for (int kq = 0; kq < 2; kq++) {
            bf16x8 af[4], bfr[4];
            const int c = ((((kq << 2) | quad) ^ sA) << 3);
#pragma unroll
            for (int i = 0; i < 4; i++)
                af[i] = *(const bf16x8*)&sm[bs][0][(wm + i * 16 + l16) * 64 + c];
#pragma unroll
            for (int j = 0; j < 4; j++)
                bfr[j] = *(const bf16x8*)&sm[bs][1][(wn + j * 16 + l16) * 64 + c];
            __builtin_amdgcn_s_setprio(1);
#pragma unroll
            for (int i = 0; i < 4; i++)
#pragma unroll
                for (int j = 0; j < 4; j++)
                    acc[i][j] = SWAP
                        ? __builtin_amdgcn_mfma_f32_16x16x32_bf16(bfr[j], af[i], acc[i][j], 0, 0, 0)
                        : __builtin_amdgcn_mfma_f32_16x16x32_bf16(af[i], bfr[j], acc[i][j], 0, 0, 0);
            __builtin_amdgcn_s_setprio(0);
        }
        __builtin_amdgcn_sched_barrier(0);
        __builtin_amdgcn_s_barrier();
    }
#undef STGQ
#undef GLLQ
}

__global__ __launch_bounds__(256) void qkv_gemm(const bf16* __restrict__ xb,
                                                const bf16* __restrict__ wtb,
                                                const float* __restrict__ bq,
                                                const float* __restrict__ bk,
                                                const float* __restrict__ bv,
                                                bf16* __restrict__ q,
                                                bf16* __restrict__ k,
                                                bf16* __restrict__ v) {
    __shared__ __align__(16) bf16 sm[2][2][8192];   // 64 KiB
    int zc = blockIdx.x;
    int z = zc >> 3;
    const bf16* Bt = wtb + (size_t)z * D_MODEL * D_MODEL;
    const float* bias = (z == 0) ? bq : (z == 1) ? bk : bv;
    int row0 = blockIdx.y * 128, col0 = (zc & 7) * 128;
    f32x4 acc[4][4] = {};

    const int lane = threadIdx.x & 63, wave = threadIdx.x >> 6;
    const int quad = lane >> 4, l16 = lane & 15;
    const int wm = (wave & 1) << 6, wn = (wave >> 1) << 6;

    if (z < 2) {
        gemm_core128<false>(xb, Bt, row0, col0, sm, acc);
        bf16* dst = (z == 0) ? q : k;
        const float sc = (z == 0) ? Q_SCALE : 1.0f;
#pragma unroll
        for (int i = 0; i < 4; i++) {
#pragma unroll
            for (int j = 0; j < 4; j++) {
                int colg = col0 + wn + j * 16 + l16;          // feature 0..1023
                int hh = colg >> 6, d = colg & 63;
                float bi = bias[colg];
                int rbase = row0 + wm + i * 16 + quad * 4;     // token of reg 0
                int b = rbase >> 11, sb = rbase & 2047;
#pragma unroll
                for (int r = 0; r < 4; r++) {
                    size_t idx = ((size_t)(b * NHEAD + hh) * SEQ + sb + r) * DEPTH + d;
                    dst[idx] = (bf16)((acc[i][j][r] + bi) * sc);
                }
            }
        }
    } else {
        gemm_core128<true>(xb, Bt, row0, col0, sm, acc);
        // acc[i][j] = C^T tile: row(quad*4+r) = feature, col(l16) = token
#pragma unroll
        for (int i = 0; i < 4; i++) {
            int tok = row0 + wm + i * 16 + l16;
            int b = tok >> 11, sb = tok & 2047;
#pragma unroll
            for (int j = 0; j < 4; j++) {
#pragma unroll
                for (int r = 0; r < 4; r++) {
                    int f = col0 + wn + j * 16 + quad * 4 + r;
                    int hh = f >> 6, d = f & 63;
                    v[((size_t)(b * NHEAD + hh) * DEPTH + d) * SEQ + sb] =
                        (bf16)(acc[i][j][r] + bias[f]);
                }
            }
        }
    }
}

// ---------------------------------------------------------------------------
// Kernel 3: flash attention, R13 (unchanged: 8-wave 2qg x 4ks kv-split,
// shared per-slice dbuf staging by qg0, counted vmcnt(8), V-swizzle fix).
// ---------------------------------------------------------------------------
__global__ __launch_bounds__(512, 4) void attn(const bf16* __restrict__ q,
                                               const bf16* __restrict__ k,
                                               const bf16* __restrict__ v,
                                               bf16* __restrict__ ctx) {
    __shared__ __align__(16) bf16 smb[32768];   // 64 KB: 4 slices x 16 KB
    const int tid = threadIdx.x;
    const int lane = tid & 63, wave = tid >> 6;   // 8 waves
    const int ks = wave & 3, qg = wave >> 2;
    const int quad = lane >> 4, l16 = lane & 15;
    const int bh = blockIdx.x;
    const int q0 = blockIdx.y * 64;
    const size_t hb = (size_t)bh * SEQ * DEPTH;
    const bf16* qh = q + hb;
    const bf16* kh = k + hb;            // [S][64]
    const bf16* vh = v + hb;            // [64][S]

    // Q as B-fragments: this wave's 32 q rows (qg half)
    bf16x8 bq_[2][2];
#pragma unroll
    for (int n = 0; n < 2; n++) {
        int qrow = q0 + qg * 32 + n * 16 + l16;
#pragma unroll
        for (int c = 0; c < 2; c++)
            bq_[n][c] = *(const bf16x8*)&qh[(size_t)qrow * DEPTH + c * 32 + quad * 8];
    }

    f32x4 ov[4][2] = {};        // [d-tile][q-tile] kv-partial ctx^T
    float lvs[2] = {0.f, 0.f};  // [q-tile] quad-partial row sums

    // slice LDS base (elems): K at sb + buf*2048, V at sb + 4096 + buf*2048
    const int sb = ks * 8192;
    // staging source swizzles (used by qg==0 only)
    const int kchS = (lane & 7) ^ (((lane >> 3) & 3) << 1);   // ^ (o&1) per o
    const int vchS = (lane & 3) ^ ((lane >> 3) & 3);          // s(d) = (d>>1)&3
    // fragment-read geometry
    const int krdL = ((l16 >> 2) << 3) + (l16 & 3);           // local row, + h*4
    const int ksw = ((l16 & 3) << 1) | ((l16 >> 2) & 1);      // = s(row)
    const int vsw = (quad ^ ((l16 >> 1) & 3)) << 3;           // V read chunk

#define GLL(SRC, DST) __builtin_amdgcn_global_load_lds((gbl_void*)(SRC), (lds_void*)(DST), 16, 0, 0)

#define STAGE(BUF_, T_) { \
    _Pragma("unroll") \
    for (int o_ = 0; o_ < 4; o_++) { \
        const bf16* s_ = kh + (size_t)((T_) + ks * 32 + o_ * 8 + (lane >> 3)) * DEPTH \
                       + ((kchS ^ (o_ & 1)) << 3); \
        GLL(s_, smb + sb + (BUF_) * 2048 + o_ * 512 + lane * 8); \
    } \
    _Pragma("unroll") \
    for (int o_ = 0; o_ < 4; o_++) { \
        const bf16* s_ = vh + (size_t)(o_ * 16 + (lane >> 2)) * SEQ + (T_) + ks * 32 \
                       + (vchS << 3); \
        GLL(s_, smb + sb + 4096 + (BUF_) * 2048 + o_ * 512 + lane * 8); \
    } }

#define COMPUTE(BUF_) { \
    f32x4 s[2][2] = {}; \
    __builtin_amdgcn_s_setprio(1); \
    _Pragma("unroll") \
    for (int c_ = 0; c_ < 2; c_++) \
        _Pragma("unroll") \
        for (int h_ = 0; h_ < 2; h_++) { \
            bf16x8 kf = *(const bf16x8*)&smb[sb + (BUF_) * 2048 + (krdL + h_ * 4) * 64 \
                                             + ((((c_ << 2) | quad) ^ ksw) << 3)]; \
            _Pragma("unroll") \
            for (int n_ = 0; n_ < 2; n_++) \
                s[h_][n_] = __builtin_amdgcn_mfma_f32_16x16x32_bf16(kf, bq_[n_][c_], s[h_][n_], 0, 0, 0); \
        } \
    __builtin_amdgcn_s_setprio(0); \
    bf16x8 pb[2]; \
    _Pragma("unroll") \
    for (int n_ = 0; n_ < 2; n_++) { \
        float e0 = __builtin_amdgcn_exp2f(s[0][n_][0]); \
        float e1 = __builtin_amdgcn_exp2f(s[0][n_][1]); \
        float e2 = __builtin_amdgcn_exp2f(s[0][n_][2]); \
        float e3 = __builtin_amdgcn_exp2f(s[0][n_][3]); \
        float e4 = __builtin_amdgcn_exp2f(s[1][n_][0]); \
        float e5 = __builtin_amdgcn_exp2f(s[1][n_][1]); \
        float e6 = __builtin_amdgcn_exp2f(s[1][n_][2]); \
        float e7 = __builtin_amdgcn_exp2f(s[1][n_][3]); \
        pb[n_][0] = (bf16)e0; pb[n_][1] = (bf16)e1; \
        pb[n_][2] = (bf16)e2; pb[n_][3] = (bf16)e3; \
        pb[n_][4] = (bf16)e4; pb[n_][5] = (bf16)e5; \
        pb[n_][6] = (bf16)e6; pb[n_][7] = (bf16)e7; \
        lvs[n_] += ((e0 + e1) + (e2 + e3)) + ((e4 + e5) + (e6 + e7)); \
    } \
    __builtin_amdgcn_s_setprio(1); \
    _Pragma("unroll") \
    for (int t_ = 0; t_ < 4; t_++) { \
        bf16x8 vf = *(const bf16x8*)&smb[sb + 4096 + (BUF_) * 2048 + (t_ * 16 + l16) * 32 + vsw]; \
        _Pragma("unroll") \
        for (int n_ = 0; n_ < 2; n_++) \
            ov[t_][n_] = __builtin_amdgcn_mfma_f32_16x16x32_bf16(vf, pb[n_], ov[t_][n_], 0, 0, 0); \
    } \
    __builtin_amdgcn_s_setprio(0); }

#define SB0 __builtin_amdgcn_sched_barrier(0)

    if (qg == 0) STAGE(0, 0);
#pragma unroll 1
    for (int i = 0; i < 16; i++) {
        if (qg == 0) {
            if (i < 15) {
                STAGE((i + 1) & 1, (i + 1) * 128);
                asm volatile("s_waitcnt vmcnt(8)" ::: "memory");
            } else {
                asm volatile("s_waitcnt vmcnt(0)" ::: "memory");
            }
        }
        SB0;
        __builtin_amdgcn_s_barrier();   // tile i staged data visible
        COMPUTE(i & 1);
        SB0;
        __builtin_amdgcn_s_barrier();   // all reads of buf done before reuse
    }

#undef SB0
#undef COMPUTE
#undef STAGE
#undef GLL

    // ---- cross-slice reduction: partials over ks per (qg, t, n) ----
    f32x4* Red  = (f32x4*)smb;                       // [2qg][2t][2n][4ks][64]
    float* Lred = (float*)((char*)smb + 32768);      // [2qg][2n][4ks][64]
    const int b = bh >> 4, hh = bh & 15;
    const int tA = ks >> 1, nA = ks & 1;

    __syncthreads();
#pragma unroll
    for (int t2 = 0; t2 < 2; t2++)
#pragma unroll
        for (int n = 0; n < 2; n++)
            Red[((((qg * 2 + t2) * 2 + n) * 4) + ks) * 64 + lane] = ov[t2][n];
#pragma unroll
    for (int n = 0; n < 2; n++)
        Lred[((qg * 2 + n) * 4 + ks) * 64 + lane] = lvs[n];
    __syncthreads();

    float ls0 = 0.f, ls1 = 0.f;
#pragma unroll
    for (int k4 = 0; k4 < 4; k4++)
#pragma unroll
        for (int qd = 0; qd < 4; qd++) {
            ls0 += Lred[((qg * 2 + 0) * 4 + k4) * 64 + qd * 16 + l16];
            ls1 += Lred[((qg * 2 + 1) * 4 + k4) * 64 + qd * 16 + l16];
        }
    const float lsn = (ks & 1) ? ls1 : ls0;
    const float iv = 1.0f / lsn;

    {
        f32x4 sv = Red[((((qg * 2 + tA) * 2 + nA) * 4) + 0) * 64 + lane]
                 + Red[((((qg * 2 + tA) * 2 + nA) * 4) + 1) * 64 + lane]
                 + Red[((((qg * 2 + tA) * 2 + nA) * 4) + 2) * 64 + lane]
                 + Red[((((qg * 2 + tA) * 2 + nA) * 4) + 3) * 64 + lane];
        bf16x4 ob = {(bf16)(sv[0] * iv), (bf16)(sv[1] * iv),
                     (bf16)(sv[2] * iv), (bf16)(sv[3] * iv)};
        size_t off = ((size_t)(b * SEQ + q0 + qg * 32 + nA * 16 + l16)) * D_MODEL
                   + hh * 64 + tA * 16 + quad * 4;
        *(bf16x4*)&ctx[off] = ob;
    }
    __syncthreads();
#pragma unroll
    for (int t2 = 0; t2 < 2; t2++)
#pragma unroll
        for (int n = 0; n < 2; n++)
            Red[((((qg * 2 + t2) * 2 + n) * 4) + ks) * 64 + lane] = ov[2 + t2][n];
    __syncthreads();
    {
        f32x4 sv = Red[((((qg * 2 + tA) * 2 + nA) * 4) + 0) * 64 + lane]
                 + Red[((((qg * 2 + tA) * 2 + nA) * 4) + 1) * 64 + lane]
                 + Red[((((qg * 2 + tA) * 2 + nA) * 4) + 2) * 64 + lane]
                 + Red[((((qg * 2 + tA) * 2 + nA) * 4) + 3) * 64 + lane];
        bf16x4 ob = {(bf16)(sv[0] * iv), (bf16)(sv[1] * iv),
                     (bf16)(sv[2] * iv), (bf16)(sv[3] * iv)};
        size_t off = ((size_t)(b * SEQ + q0 + qg * 32 + nA * 16 + l16)) * D_MODEL
                   + hh * 64 + (2 + tA) * 16 + quad * 4;
        *(bf16x4*)&ctx[off] = ob;
    }
}

// ---------------------------------------------------------------------------
// Kernel 4: output projection (R6-measured version, unchanged).
// ---------------------------------------------------------------------------
__global__ __launch_bounds__(256) void out_gemm(const bf16* __restrict__ ctx,
                                                const bf16* __restrict__ wot,
                                                const float* __restrict__ bo,
                                                float* __restrict__ out) {
    __shared__ bf16 As[64 * 32];
    __shared__ bf16 Bs[128 * 32];
    const int tid = threadIdx.x;
    const int lane = tid & 63, wave = tid >> 6;
    const int quad = lane >> 4, l16 = lane & 15;
    const int srow = lane >> 2, selem = (lane & 3) * 8;
    int row0 = blockIdx.y * 64, col0 = blockIdx.x * 128;
    f32x4 acc[4][2] = {};

    for (int k0 = 0; k0 < D_MODEL; k0 += 32) {
        __syncthreads();
        {
            const bf16* ga = ctx + (size_t)(row0 + wave * 16 + srow) * D_MODEL + k0 + selem;
            __builtin_amdgcn_global_load_lds((gbl_void*)ga, (lds_void*)(As + wave * 512 + lane * 8), 16, 0, 0);
        }
#pragma unroll
        for (int t = 0; t < 2; t++) {
            int m = wave * 2 + t;
            const bf16* gb = wot + (size_t)(col0 + m * 16 + srow) * D_MODEL + k0 + selem;
            __builtin_amdgcn_global_load_lds((gbl_void*)gb, (lds_void*)(Bs + m * 512 + lane * 8), 16, 0, 0);
        }
        __syncthreads();
        bf16x8 af[4], bfr[2];
#pragma unroll
        for (int i = 0; i < 4; i++)
            af[i] = *(const bf16x8*)&As[(i * 16 + l16) * 32 + quad * 8];
#pragma unroll
        for (int j = 0; j < 2; j++)
            bfr[j] = *(const bf16x8*)&Bs[(wave * 32 + j * 16 + l16) * 32 + quad * 8];
#pragma unroll
        for (int i = 0; i < 4; i++)
#pragma unroll
            for (int j = 0; j < 2; j++)
                acc[i][j] = __builtin_amdgcn_mfma_f32_16x16x32_bf16(af[i], bfr[j], acc[i][j], 0, 0, 0);
    }
#pragma unroll
    for (int i = 0; i < 4; i++)
#pragma unroll
        for (int j = 0; j < 2; j++) {
            int colg = col0 + wave * 32 + j * 16 + l16;
            float bi = bo[colg];
            int rbase = row0 + i * 16 + quad * 4;
#pragma unroll
            for (int r = 0; r < 4; r++)
                out[(size_t)(rbase + r) * D_MODEL + colg] = acc[i][j][r] + bi;
        }
}

// ---------------------------------------------------------------------------
extern "C" void kernel_launch(void* const* d_in, const int* in_sizes, int n_in,
                              void* d_out, int out_size, void* d_ws, size_t ws_size,
                              hipStream_t stream) {
    const float* x  = (const float*)d_in[0];
    const float* wq = (const float*)d_in[1];
    const float* bq = (const float*)d_in[2];
    const float* wk = (const float*)d_in[3];
    const float* bk = (const float*)d_in[4];
    const float* wv = (const float*)d_in[5];
    const float* bv = (const float*)d_in[6];
    const float* wo = (const float*)d_in[7];
    const float* bo = (const float*)d_in[8];
    float* out = (float*)d_out;

    const size_t MB = 1024 * 1024;
    char* ws = (char*)d_ws;
    bf16* xb  = (bf16*)(ws);             // [4096][1024]            8 MB
    bf16* wtb = (bf16*)(ws + 8 * MB);    // [4][1024][1024] (N,K)   8 MB
    bf16* qb  = (bf16*)(ws + 16 * MB);   // [B,H,S,64] (scaled)     8 MB
    bf16* kb  = (bf16*)(ws + 24 * MB);   // [B,H,S,64]              8 MB
    bf16* vb  = (bf16*)(ws + 32 * MB);   // [B,H,64,S]              8 MB
    bf16* ctx = (bf16*)(ws + 40 * MB);   // [4096][1024]            8 MB

    prep<<<dim3(32, 32, 8), dim3(32, 8), 0, stream>>>(wq, wk, wv, wo, x, wtb, xb);
    qkv_gemm<<<dim3(24, 32), 256, 0, stream>>>(xb, wtb, bq, bk, bv, qb, kb, vb);
    attn<<<dim3(BATCH * NHEAD, SEQ / 64), dim3(512), 0, stream>>>(qb, kb, vb, ctx);
    out_gemm<<<dim3(8, 64), 256, 0, stream>>>(ctx, wtb + 3 * (size_t)D_MODEL * D_MODEL, bo, out);
}